// Round 11
// baseline (1200.383 us; speedup 1.0000x reference)
//
#include <hip/hip_runtime.h>

using bf16x8 = __attribute__((ext_vector_type(8))) short;
using f32x4  = __attribute__((ext_vector_type(4))) float;

#define DEV static __device__ __forceinline__

constexpr int SEQ    = 1040;
constexpr int MDIM   = 2048;
constexpr int NH     = 16;
constexpr int HD     = 128;
constexpr int NCACHE = 8320;
constexpr int LTOT   = NCACHE + SEQ;   // 9360

DEV float b2f(unsigned short u) {
  union { unsigned int i; float f; } z; z.i = ((unsigned int)u) << 16; return z.f;
}
DEV unsigned short f2b(float f) {
  union { float f; unsigned int i; } z; z.f = f;
  return (unsigned short)((z.i + 0x7fffu + ((z.i >> 16) & 1u)) >> 16);
}

// ---------- GEMM: out[row,col] = sum_k A[row,k] * W[k,col] + bias[col]
// aLay 0: A fp32 row-major [row][2048]; aLay 1: A bf16 head-scattered [h][SEQ][128]
// oMode 2: bf16 head-scattered [h][SEQ][128]; oMode 3: FP32 row-major [row][2048]
__global__ __launch_bounds__(256) void gemm_k(
    const void* __restrict__ Ap, const float* __restrict__ W,
    const float* __restrict__ bias, void* __restrict__ outp,
    int aLay, int oMode) {
  __shared__ short As[128][40];
  __shared__ short Bs[128][40];
  const int tid = threadIdx.x;
  const int l = tid & 63, wv = tid >> 6;
  const int l16 = l & 15, kl = l >> 4;
  const int m0 = blockIdx.y * 128, n0 = blockIdx.x * 128;
  const int wm = (wv >> 1) * 64, wn = (wv & 1) * 64;
  const int nq = tid >> 4, kh = tid & 15;  // B staging map
  f32x4 acc[4][4] = {};
  for (int k0 = 0; k0 < MDIM; k0 += 32) {
    // ---- stage A tile [128 rows][32 k] as bf16
#pragma unroll
    for (int it = 0; it < 2; ++it) {
      int slot = tid + it * 256;
      int m = slot >> 2, kq = slot & 3;
      int row = m0 + m, k = k0 + kq * 8;
      bf16x8 v = {0, 0, 0, 0, 0, 0, 0, 0};
      if (row < SEQ) {
        if (aLay == 0) {
          const float* Af = (const float*)Ap + (size_t)row * MDIM + k;
          f32x4 f0 = *(const f32x4*)(Af);
          f32x4 f1 = *(const f32x4*)(Af + 4);
#pragma unroll
          for (int i = 0; i < 4; ++i) { v[i] = (short)f2b(f0[i]); v[4 + i] = (short)f2b(f1[i]); }
        } else {
          const unsigned short* Ab = (const unsigned short*)Ap;
          v = *(const bf16x8*)(Ab + ((size_t)(k >> 7) * SEQ + row) * HD + (k & 127));
        }
      }
      *(bf16x8*)&As[m][kq * 8] = v;
    }
    // ---- stage B tile transposed: Bs[n][k] = bf16(W[k0+k][n0+n])
    {
      const float* Wp = W + (size_t)(k0 + kh * 2) * MDIM + n0 + nq * 8;
      f32x4 a0 = *(const f32x4*)(Wp);
      f32x4 a1 = *(const f32x4*)(Wp + 4);
      f32x4 b0 = *(const f32x4*)(Wp + MDIM);
      f32x4 b1 = *(const f32x4*)(Wp + MDIM + 4);
#pragma unroll
      for (int i = 0; i < 4; ++i) {
        short2 p0; p0.x = (short)f2b(a0[i]); p0.y = (short)f2b(b0[i]);
        *(short2*)&Bs[nq * 8 + i][kh * 2] = p0;
        short2 p1; p1.x = (short)f2b(a1[i]); p1.y = (short)f2b(b1[i]);
        *(short2*)&Bs[nq * 8 + 4 + i][kh * 2] = p1;
      }
    }
    __syncthreads();
    bf16x8 aF[4], bF[4];
#pragma unroll
    for (int mi = 0; mi < 4; ++mi)
      aF[mi] = *(const bf16x8*)&As[wm + mi * 16 + l16][kl * 8];
#pragma unroll
    for (int ni = 0; ni < 4; ++ni)
      bF[ni] = *(const bf16x8*)&Bs[wn + ni * 16 + l16][kl * 8];
#pragma unroll
    for (int mi = 0; mi < 4; ++mi)
#pragma unroll
      for (int ni = 0; ni < 4; ++ni)
        acc[mi][ni] = __builtin_amdgcn_mfma_f32_16x16x32_bf16(
            aF[mi], bF[ni], acc[mi][ni], 0, 0, 0);
    __syncthreads();
  }
#pragma unroll
  for (int ni = 0; ni < 4; ++ni) {
    const int col = n0 + wn + ni * 16 + l16;
    const float bb = bias[col];
#pragma unroll
    for (int mi = 0; mi < 4; ++mi) {
      const int rowb = m0 + wm + mi * 16 + kl * 4;
#pragma unroll
      for (int r = 0; r < 4; ++r) {
        const int row = rowb + r;
        if (row >= SEQ) continue;
        const float val = acc[mi][ni][r] + bb;
        if (oMode == 2) {
          ((unsigned short*)outp)[((size_t)(col >> 7) * SEQ + row) * HD + (col & 127)] = f2b(val);
        } else {
          ((float*)outp)[(size_t)row * MDIM + col] = val;   // FP32 final output
        }
      }
    }
  }
}

// ---------- RMSNorm + RoPE, in place on [h][SEQ][128] bf16 ----------
__global__ __launch_bounds__(256) void rmsrope_k(
    unsigned short* __restrict__ Qb, unsigned short* __restrict__ Kn,
    const float* __restrict__ gq, const float* __restrict__ gk,
    const float* __restrict__ fr) {
  const int s = blockIdx.x, which = blockIdx.y;
  unsigned short* B = which ? Kn : Qb;
  const float* g = which ? gk : gq;
  __shared__ float cs[64], sn[64], red[4];
  const int t = threadIdx.x;
  if (t < 64) {
    float a = fr[s * 64 + t];
    cs[t] = cosf(a);
    sn[t] = sinf(a);
  }
  const int c0 = t * 8;
  const int hh = c0 >> 7, dd = c0 & 127, p0 = dd >> 1;
  const size_t addr = ((size_t)hh * SEQ + s) * HD + dd;
  bf16x8 v = *(const bf16x8*)(B + addr);
  float y[8];
#pragma unroll
  for (int i = 0; i < 8; ++i) y[i] = b2f((unsigned short)v[i]);
  float ssq = 0.f;
#pragma unroll
  for (int i = 0; i < 8; ++i) ssq += y[i] * y[i];
#pragma unroll
  for (int off = 32; off; off >>= 1) ssq += __shfl_xor(ssq, off);
  if ((t & 63) == 0) red[t >> 6] = ssq;
  __syncthreads();
  const float var = (red[0] + red[1] + red[2] + red[3]) * (1.0f / MDIM);
  const float rs = rsqrtf(var + 1e-6f);
  bf16x8 ov;
#pragma unroll
  for (int i = 0; i < 4; ++i) {
    float e = b2f(f2b(y[2 * i] * rs)) * g[c0 + 2 * i];
    float o = b2f(f2b(y[2 * i + 1] * rs)) * g[c0 + 2 * i + 1];
    float C = cs[p0 + i], S = sn[p0 + i];
    ov[2 * i]     = (short)f2b(e * C - o * S);
    ov[2 * i + 1] = (short)f2b(e * S + o * C);
  }
  *(bf16x8*)(B + addr) = ov;
}

// ---------- flash attention: one (head, 64-row q tile) per block, 4 waves ----------
// Output written in place into Qb ([h][SEQ][128]): block reads only its own region
// (at kernel start) and writes exactly that region (at kernel end).
__global__ __launch_bounds__(256) void attn_k(
    unsigned short* __restrict__ Qb, const unsigned short* __restrict__ Kn,
    const unsigned short* __restrict__ Vn, const float* __restrict__ Kc,
    const float* __restrict__ Vc) {
  __shared__ short Kl[64][136];     // [j][d], padded
  __shared__ short Vt[128][72];     // [d][j], transposed, padded
  __shared__ short Pl[4][16][72];   // per-wave P tile [q][j]
  const int h = blockIdx.y, qt = blockIdx.x;
  const int tid = threadIdx.x, wv = tid >> 6, l = tid & 63;
  const int l16 = l & 15, kl = l >> 4;
  const float SCALE = 0.08838834764831845f;  // 1/sqrt(128)

  int qrow = qt * 64 + wv * 16 + l16;
  if (qrow > SEQ - 1) qrow = SEQ - 1;
  bf16x8 qf[4];
#pragma unroll
  for (int kk = 0; kk < 4; ++kk)
    qf[kk] = *(const bf16x8*)(Qb + ((size_t)h * SEQ + qrow) * HD + kk * 32 + kl * 8);

  f32x4 oacc[8] = {};
  float mrow[4] = {-1e30f, -1e30f, -1e30f, -1e30f};
  float lrow[4] = {0.f, 0.f, 0.f, 0.f};

  for (int kv0 = 0; kv0 < LTOT; kv0 += 64) {
#pragma unroll
    for (int it = 0; it < 4; ++it) {
      int slot = tid + it * 256;
      int j = slot & 63, dq = slot >> 6;
      int jg = kv0 + j;
      bf16x8 kvv = {0,0,0,0,0,0,0,0}, vvv = {0,0,0,0,0,0,0,0};
      if (jg < NCACHE) {
        const float* kp = Kc + ((size_t)jg * NH + h) * HD + dq * 8;
        const float* vp = Vc + ((size_t)jg * NH + h) * HD + dq * 8;
        f32x4 ka = *(const f32x4*)(kp), kb = *(const f32x4*)(kp + 4);
        f32x4 va = *(const f32x4*)(vp), vb = *(const f32x4*)(vp + 4);
#pragma unroll
        for (int i = 0; i < 4; ++i) {
          kvv[i] = (short)f2b(ka[i]); kvv[4 + i] = (short)f2b(kb[i]);
          vvv[i] = (short)f2b(va[i]); vvv[4 + i] = (short)f2b(vb[i]);
        }
      } else if (jg < LTOT) {
        kvv = *(const bf16x8*)(Kn + ((size_t)h * SEQ + (jg - NCACHE)) * HD + dq * 8);
        vvv = *(const bf16x8*)(Vn + ((size_t)h * SEQ + (jg - NCACHE)) * HD + dq * 8);
      }
      *(bf16x8*)&Kl[j][dq * 8] = kvv;
#pragma unroll
      for (int i = 0; i < 8; ++i) Vt[dq * 8 + i][j] = vvv[i];
    }
    __syncthreads();

    // S = Q K^T
    f32x4 sa[4] = {};
#pragma unroll
    for (int ni = 0; ni < 4; ++ni)
#pragma unroll
      for (int kk = 0; kk < 4; ++kk) {
        bf16x8 bK = *(const bf16x8*)&Kl[ni * 16 + l16][kk * 32 + kl * 8];
        sa[ni] = __builtin_amdgcn_mfma_f32_16x16x32_bf16(qf[kk], bK, sa[ni], 0, 0, 0);
      }

    // online softmax (rows kl*4+r, cols ni*16+l16)
    float sv[4][4];
    float pm[4] = {-1e30f, -1e30f, -1e30f, -1e30f};
#pragma unroll
    for (int ni = 0; ni < 4; ++ni) {
      int jg = kv0 + ni * 16 + l16;
      bool valid = jg < LTOT;
#pragma unroll
      for (int r = 0; r < 4; ++r) {
        float xs = valid ? sa[ni][r] * SCALE : -1e30f;
        sv[ni][r] = xs;
        pm[r] = fmaxf(pm[r], xs);
      }
    }
#pragma unroll
    for (int off = 1; off < 16; off <<= 1)
#pragma unroll
      for (int r = 0; r < 4; ++r) pm[r] = fmaxf(pm[r], __shfl_xor(pm[r], off));

    float sc[4];
#pragma unroll
    for (int r = 0; r < 4; ++r) {
      float mn = fmaxf(mrow[r], pm[r]);
      sc[r] = __expf(mrow[r] - mn);
      mrow[r] = mn;
    }
    float ps[4] = {0.f, 0.f, 0.f, 0.f};
#pragma unroll
    for (int ni = 0; ni < 4; ++ni)
#pragma unroll
      for (int r = 0; r < 4; ++r) {
        float p = __expf(sv[ni][r] - mrow[r]);
        sv[ni][r] = p;
        ps[r] += p;
      }
#pragma unroll
    for (int off = 1; off < 16; off <<= 1)
#pragma unroll
      for (int r = 0; r < 4; ++r) ps[r] += __shfl_xor(ps[r], off);
#pragma unroll
    for (int r = 0; r < 4; ++r) lrow[r] = lrow[r] * sc[r] + ps[r];
#pragma unroll
    for (int di = 0; di < 8; ++di)
#pragma unroll
      for (int r = 0; r < 4; ++r) oacc[di][r] *= sc[r];
#pragma unroll
    for (int ni = 0; ni < 4; ++ni)
#pragma unroll
      for (int r = 0; r < 4; ++r)
        Pl[wv][kl * 4 + r][ni * 16 + l16] = (short)f2b(sv[ni][r]);
    __syncthreads();

    // O += P V
#pragma unroll
    for (int di = 0; di < 8; ++di)
#pragma unroll
      for (int k2 = 0; k2 < 2; ++k2) {
        bf16x8 aP = *(const bf16x8*)&Pl[wv][l16][k2 * 32 + kl * 8];
        bf16x8 bV = *(const bf16x8*)&Vt[di * 16 + l16][k2 * 32 + kl * 8];
        oacc[di] = __builtin_amdgcn_mfma_f32_16x16x32_bf16(aP, bV, oacc[di], 0, 0, 0);
      }
    __syncthreads();
  }

  const int qb = qt * 64 + wv * 16 + kl * 4;
#pragma unroll
  for (int r = 0; r < 4; ++r) {
    int q = qb + r;
    if (q < SEQ) {
      float inv = 1.0f / lrow[r];
#pragma unroll
      for (int di = 0; di < 8; ++di)
        Qb[((size_t)h * SEQ + q) * HD + di * 16 + l16] = f2b(oacc[di][r] * inv);
    }
  }
}

extern "C" void kernel_launch(void* const* d_in, const int* in_sizes, int n_in,
                              void* d_out, int out_size, void* d_ws, size_t ws_size,
                              hipStream_t stream) {
  const float* x  = (const float*)d_in[0];
  const float* fr = (const float*)d_in[2];
  const float* Kc = (const float*)d_in[3];
  const float* Vc = (const float*)d_in[4];
  const float* Wq = (const float*)d_in[5];
  const float* bq = (const float*)d_in[6];
  const float* Wk = (const float*)d_in[7];
  const float* bk = (const float*)d_in[8];
  const float* Wv = (const float*)d_in[9];
  const float* bv = (const float*)d_in[10];
  const float* Wo = (const float*)d_in[11];
  const float* bo = (const float*)d_in[12];
  const float* gq = (const float*)d_in[13];
  const float* gk = (const float*)d_in[14];

  // ws: 3 bf16 buffers of [NH][SEQ][HD] = 12.8 MB (ws health verified by r8 canary)
  unsigned short* Qb = (unsigned short*)d_ws;
  unsigned short* Kn = Qb + (size_t)NH * SEQ * HD;
  unsigned short* Vn = Kn + (size_t)NH * SEQ * HD;

  const dim3 gg(16, 9);
  gemm_k<<<gg, 256, 0, stream>>>(x, Wq, bq, Qb, 0, 2);
  gemm_k<<<gg, 256, 0, stream>>>(x, Wk, bk, Kn, 0, 2);
  gemm_k<<<gg, 256, 0, stream>>>(x, Wv, bv, Vn, 0, 2);
  rmsrope_k<<<dim3(SEQ, 2), 256, 0, stream>>>(Qb, Kn, gq, gk, fr);
  attn_k<<<dim3(17, NH), 256, 0, stream>>>(Qb, Kn, Vn, Kc, Vc);
  gemm_k<<<gg, 256, 0, stream>>>(Qb, Wo, bo, d_out, 1, 3);   // FP32 final output
}

// Round 12
// 855.960 us; speedup vs baseline: 1.4024x; 1.4024x over previous
//
#include <hip/hip_runtime.h>

using bf16x8 = __attribute__((ext_vector_type(8))) short;
using f32x4  = __attribute__((ext_vector_type(4))) float;

#define DEV static __device__ __forceinline__

constexpr int SEQ    = 1040;
constexpr int MDIM   = 2048;
constexpr int NH     = 16;
constexpr int HD     = 128;
constexpr int NCACHE = 8320;
constexpr int LTOT   = NCACHE + SEQ;   // 9360
constexpr int NQT    = 17;             // ceil(SEQ/64)

DEV float b2f(unsigned short u) {
  union { unsigned int i; float f; } z; z.i = ((unsigned int)u) << 16; return z.f;
}
DEV unsigned short f2b(float f) {
  union { float f; unsigned int i; } z; z.f = f;
  return (unsigned short)((z.i + 0x7fffu + ((z.i >> 16) & 1u)) >> 16);
}

// ---------- GEMM (unchanged, passing) ----------
__global__ __launch_bounds__(256) void gemm_k(
    const void* __restrict__ Ap, const float* __restrict__ W,
    const float* __restrict__ bias, void* __restrict__ outp,
    int aLay, int oMode) {
  __shared__ short As[128][40];
  __shared__ short Bs[128][40];
  const int tid = threadIdx.x;
  const int l = tid & 63, wv = tid >> 6;
  const int l16 = l & 15, kl = l >> 4;
  const int m0 = blockIdx.y * 128, n0 = blockIdx.x * 128;
  const int wm = (wv >> 1) * 64, wn = (wv & 1) * 64;
  const int nq = tid >> 4, kh = tid & 15;
  f32x4 acc[4][4] = {};
  for (int k0 = 0; k0 < MDIM; k0 += 32) {
#pragma unroll
    for (int it = 0; it < 2; ++it) {
      int slot = tid + it * 256;
      int m = slot >> 2, kq = slot & 3;
      int row = m0 + m, k = k0 + kq * 8;
      bf16x8 v = {0, 0, 0, 0, 0, 0, 0, 0};
      if (row < SEQ) {
        if (aLay == 0) {
          const float* Af = (const float*)Ap + (size_t)row * MDIM + k;
          f32x4 f0 = *(const f32x4*)(Af);
          f32x4 f1 = *(const f32x4*)(Af + 4);
#pragma unroll
          for (int i = 0; i < 4; ++i) { v[i] = (short)f2b(f0[i]); v[4 + i] = (short)f2b(f1[i]); }
        } else {
          const unsigned short* Ab = (const unsigned short*)Ap;
          v = *(const bf16x8*)(Ab + ((size_t)(k >> 7) * SEQ + row) * HD + (k & 127));
        }
      }
      *(bf16x8*)&As[m][kq * 8] = v;
    }
    {
      const float* Wp = W + (size_t)(k0 + kh * 2) * MDIM + n0 + nq * 8;
      f32x4 a0 = *(const f32x4*)(Wp);
      f32x4 a1 = *(const f32x4*)(Wp + 4);
      f32x4 b0 = *(const f32x4*)(Wp + MDIM);
      f32x4 b1 = *(const f32x4*)(Wp + MDIM + 4);
#pragma unroll
      for (int i = 0; i < 4; ++i) {
        short2 p0; p0.x = (short)f2b(a0[i]); p0.y = (short)f2b(b0[i]);
        *(short2*)&Bs[nq * 8 + i][kh * 2] = p0;
        short2 p1; p1.x = (short)f2b(a1[i]); p1.y = (short)f2b(b1[i]);
        *(short2*)&Bs[nq * 8 + 4 + i][kh * 2] = p1;
      }
    }
    __syncthreads();
    bf16x8 aF[4], bF[4];
#pragma unroll
    for (int mi = 0; mi < 4; ++mi)
      aF[mi] = *(const bf16x8*)&As[wm + mi * 16 + l16][kl * 8];
#pragma unroll
    for (int ni = 0; ni < 4; ++ni)
      bF[ni] = *(const bf16x8*)&Bs[wn + ni * 16 + l16][kl * 8];
#pragma unroll
    for (int mi = 0; mi < 4; ++mi)
#pragma unroll
      for (int ni = 0; ni < 4; ++ni)
        acc[mi][ni] = __builtin_amdgcn_mfma_f32_16x16x32_bf16(
            aF[mi], bF[ni], acc[mi][ni], 0, 0, 0);
    __syncthreads();
  }
#pragma unroll
  for (int ni = 0; ni < 4; ++ni) {
    const int col = n0 + wn + ni * 16 + l16;
    const float bb = bias[col];
#pragma unroll
    for (int mi = 0; mi < 4; ++mi) {
      const int rowb = m0 + wm + mi * 16 + kl * 4;
#pragma unroll
      for (int r = 0; r < 4; ++r) {
        const int row = rowb + r;
        if (row >= SEQ) continue;
        const float val = acc[mi][ni][r] + bb;
        if (oMode == 2) {
          ((unsigned short*)outp)[((size_t)(col >> 7) * SEQ + row) * HD + (col & 127)] = f2b(val);
        } else {
          ((float*)outp)[(size_t)row * MDIM + col] = val;
        }
      }
    }
  }
}

// ---------- RMSNorm + RoPE (unchanged, passing) ----------
__global__ __launch_bounds__(256) void rmsrope_k(
    unsigned short* __restrict__ Qb, unsigned short* __restrict__ Kn,
    const float* __restrict__ gq, const float* __restrict__ gk,
    const float* __restrict__ fr) {
  const int s = blockIdx.x, which = blockIdx.y;
  unsigned short* B = which ? Kn : Qb;
  const float* g = which ? gk : gq;
  __shared__ float cs[64], sn[64], red[4];
  const int t = threadIdx.x;
  if (t < 64) {
    float a = fr[s * 64 + t];
    cs[t] = cosf(a);
    sn[t] = sinf(a);
  }
  const int c0 = t * 8;
  const int hh = c0 >> 7, dd = c0 & 127, p0 = dd >> 1;
  const size_t addr = ((size_t)hh * SEQ + s) * HD + dd;
  bf16x8 v = *(const bf16x8*)(B + addr);
  float y[8];
#pragma unroll
  for (int i = 0; i < 8; ++i) y[i] = b2f((unsigned short)v[i]);
  float ssq = 0.f;
#pragma unroll
  for (int i = 0; i < 8; ++i) ssq += y[i] * y[i];
#pragma unroll
  for (int off = 32; off; off >>= 1) ssq += __shfl_xor(ssq, off);
  if ((t & 63) == 0) red[t >> 6] = ssq;
  __syncthreads();
  const float var = (red[0] + red[1] + red[2] + red[3]) * (1.0f / MDIM);
  const float rs = rsqrtf(var + 1e-6f);
  bf16x8 ov;
#pragma unroll
  for (int i = 0; i < 4; ++i) {
    float e = b2f(f2b(y[2 * i] * rs)) * g[c0 + 2 * i];
    float o = b2f(f2b(y[2 * i + 1] * rs)) * g[c0 + 2 * i + 1];
    float C = cs[p0 + i], S = sn[p0 + i];
    ov[2 * i]     = (short)f2b(e * C - o * S);
    ov[2 * i + 1] = (short)f2b(e * S + o * C);
  }
  *(bf16x8*)(B + addr) = ov;
}

// ---------- flash attention, KV-split partial kernel ----------
// grid (NQT, NH, S); block computes partial (O, m, l) over its KV chunk.
__global__ __launch_bounds__(256) void attn_part_k(
    const unsigned short* __restrict__ Qb, const unsigned short* __restrict__ Kn,
    const unsigned short* __restrict__ Vn, const float* __restrict__ Kc,
    const float* __restrict__ Vc, float* __restrict__ Opart,
    float* __restrict__ ml, int chunk) {
  __shared__ short Kl[64][136];
  __shared__ short Vt[128][72];
  __shared__ short Pl[4][16][72];
  const int h = blockIdx.y, qt = blockIdx.x, z = blockIdx.z;
  const int tid = threadIdx.x, wv = tid >> 6, l = tid & 63;
  const int l16 = l & 15, kl = l >> 4;
  const float SCALE = 0.08838834764831845f;

  const int c0 = z * chunk;
  const int cend = min(c0 + chunk, LTOT);

  int qrow = qt * 64 + wv * 16 + l16;
  if (qrow > SEQ - 1) qrow = SEQ - 1;
  bf16x8 qf[4];
#pragma unroll
  for (int kk = 0; kk < 4; ++kk)
    qf[kk] = *(const bf16x8*)(Qb + ((size_t)h * SEQ + qrow) * HD + kk * 32 + kl * 8);

  f32x4 oacc[8] = {};
  float mrow[4] = {-1e30f, -1e30f, -1e30f, -1e30f};
  float lrow[4] = {0.f, 0.f, 0.f, 0.f};

  for (int kv0 = c0; kv0 < cend; kv0 += 64) {
#pragma unroll
    for (int it = 0; it < 4; ++it) {
      int slot = tid + it * 256;
      int j = slot & 63, dq = slot >> 6;
      int jg = kv0 + j;
      bf16x8 kvv = {0,0,0,0,0,0,0,0}, vvv = {0,0,0,0,0,0,0,0};
      if (jg < NCACHE) {
        const float* kp = Kc + ((size_t)jg * NH + h) * HD + dq * 8;
        const float* vp = Vc + ((size_t)jg * NH + h) * HD + dq * 8;
        f32x4 ka = *(const f32x4*)(kp), kb = *(const f32x4*)(kp + 4);
        f32x4 va = *(const f32x4*)(vp), vb = *(const f32x4*)(vp + 4);
#pragma unroll
        for (int i = 0; i < 4; ++i) {
          kvv[i] = (short)f2b(ka[i]); kvv[4 + i] = (short)f2b(kb[i]);
          vvv[i] = (short)f2b(va[i]); vvv[4 + i] = (short)f2b(vb[i]);
        }
      } else if (jg < LTOT) {
        kvv = *(const bf16x8*)(Kn + ((size_t)h * SEQ + (jg - NCACHE)) * HD + dq * 8);
        vvv = *(const bf16x8*)(Vn + ((size_t)h * SEQ + (jg - NCACHE)) * HD + dq * 8);
      }
      *(bf16x8*)&Kl[j][dq * 8] = kvv;
#pragma unroll
      for (int i = 0; i < 8; ++i) Vt[dq * 8 + i][j] = vvv[i];
    }
    __syncthreads();

    f32x4 sa[4] = {};
#pragma unroll
    for (int ni = 0; ni < 4; ++ni)
#pragma unroll
      for (int kk = 0; kk < 4; ++kk) {
        bf16x8 bK = *(const bf16x8*)&Kl[ni * 16 + l16][kk * 32 + kl * 8];
        sa[ni] = __builtin_amdgcn_mfma_f32_16x16x32_bf16(qf[kk], bK, sa[ni], 0, 0, 0);
      }

    float sv[4][4];
    float pm[4] = {-1e30f, -1e30f, -1e30f, -1e30f};
#pragma unroll
    for (int ni = 0; ni < 4; ++ni) {
      int jg = kv0 + ni * 16 + l16;
      bool valid = jg < LTOT;
#pragma unroll
      for (int r = 0; r < 4; ++r) {
        float xs = valid ? sa[ni][r] * SCALE : -1e30f;
        sv[ni][r] = xs;
        pm[r] = fmaxf(pm[r], xs);
      }
    }
#pragma unroll
    for (int off = 1; off < 16; off <<= 1)
#pragma unroll
      for (int r = 0; r < 4; ++r) pm[r] = fmaxf(pm[r], __shfl_xor(pm[r], off));

    float sc[4];
#pragma unroll
    for (int r = 0; r < 4; ++r) {
      float mn = fmaxf(mrow[r], pm[r]);
      sc[r] = __expf(mrow[r] - mn);
      mrow[r] = mn;
    }
    float ps[4] = {0.f, 0.f, 0.f, 0.f};
#pragma unroll
    for (int ni = 0; ni < 4; ++ni)
#pragma unroll
      for (int r = 0; r < 4; ++r) {
        float p = __expf(sv[ni][r] - mrow[r]);
        sv[ni][r] = p;
        ps[r] += p;
      }
#pragma unroll
    for (int off = 1; off < 16; off <<= 1)
#pragma unroll
      for (int r = 0; r < 4; ++r) ps[r] += __shfl_xor(ps[r], off);
#pragma unroll
    for (int r = 0; r < 4; ++r) lrow[r] = lrow[r] * sc[r] + ps[r];
#pragma unroll
    for (int di = 0; di < 8; ++di)
#pragma unroll
      for (int r = 0; r < 4; ++r) oacc[di][r] *= sc[r];
#pragma unroll
    for (int ni = 0; ni < 4; ++ni)
#pragma unroll
      for (int r = 0; r < 4; ++r)
        Pl[wv][kl * 4 + r][ni * 16 + l16] = (short)f2b(sv[ni][r]);
    __syncthreads();

#pragma unroll
    for (int di = 0; di < 8; ++di)
#pragma unroll
      for (int k2 = 0; k2 < 2; ++k2) {
        bf16x8 aP = *(const bf16x8*)&Pl[wv][l16][k2 * 32 + kl * 8];
        bf16x8 bV = *(const bf16x8*)&Vt[di * 16 + l16][k2 * 32 + kl * 8];
        oacc[di] = __builtin_amdgcn_mfma_f32_16x16x32_bf16(aP, bV, oacc[di], 0, 0, 0);
      }
    __syncthreads();
  }

  // write partials (unnormalized O, running m, running l)
  const size_t pbase = (((size_t)z * NH + h) * NQT + qt);
  const int rowb = wv * 16 + kl * 4;
#pragma unroll
  for (int r = 0; r < 4; ++r) {
    const int row = rowb + r;
    float* Op = Opart + (pbase * 64 + row) * HD;
#pragma unroll
    for (int di = 0; di < 8; ++di) Op[di * 16 + l16] = oacc[di][r];
    ml[(pbase * 2 + 0) * 64 + row] = mrow[r];
    ml[(pbase * 2 + 1) * 64 + row] = lrow[r];
  }
}

// ---------- merge partials -> bf16 O in Qb (in place) ----------
__global__ __launch_bounds__(256) void attn_merge_k(
    const float* __restrict__ Opart, const float* __restrict__ ml,
    unsigned short* __restrict__ Qb, int S) {
  const int qt = blockIdx.x, h = blockIdx.y;
  const int t = threadIdx.x;
  const int row = t >> 2, d0 = (t & 3) * 32;
  const int q = qt * 64 + row;

  float M = -1e30f;
  for (int s = 0; s < S; ++s) {
    const size_t pbase = (((size_t)s * NH + h) * NQT + qt);
    M = fmaxf(M, ml[(pbase * 2 + 0) * 64 + row]);
  }
  float L = 0.f;
  float o[32];
#pragma unroll
  for (int i = 0; i < 32; ++i) o[i] = 0.f;
  for (int s = 0; s < S; ++s) {
    const size_t pbase = (((size_t)s * NH + h) * NQT + qt);
    const float ms = ml[(pbase * 2 + 0) * 64 + row];
    const float ls = ml[(pbase * 2 + 1) * 64 + row];
    const float w = __expf(ms - M);
    L += w * ls;
    const float* Op = Opart + (pbase * 64 + row) * HD + d0;
#pragma unroll
    for (int c = 0; c < 8; ++c) {
      f32x4 v = *(const f32x4*)(Op + c * 4);
#pragma unroll
      for (int i = 0; i < 4; ++i) o[c * 4 + i] += w * v[i];
    }
  }
  if (q < SEQ) {
    const float inv = 1.f / L;
    unsigned short* op = Qb + ((size_t)h * SEQ + q) * HD + d0;
#pragma unroll
    for (int i = 0; i < 32; ++i) op[i] = f2b(o[i] * inv);
  }
}

// ---------- fallback: original single-pass attention (known-passing) ----------
__global__ __launch_bounds__(256) void attn_k(
    unsigned short* __restrict__ Qb, const unsigned short* __restrict__ Kn,
    const unsigned short* __restrict__ Vn, const float* __restrict__ Kc,
    const float* __restrict__ Vc) {
  __shared__ short Kl[64][136];
  __shared__ short Vt[128][72];
  __shared__ short Pl[4][16][72];
  const int h = blockIdx.y, qt = blockIdx.x;
  const int tid = threadIdx.x, wv = tid >> 6, l = tid & 63;
  const int l16 = l & 15, kl = l >> 4;
  const float SCALE = 0.08838834764831845f;

  int qrow = qt * 64 + wv * 16 + l16;
  if (qrow > SEQ - 1) qrow = SEQ - 1;
  bf16x8 qf[4];
#pragma unroll
  for (int kk = 0; kk < 4; ++kk)
    qf[kk] = *(const bf16x8*)(Qb + ((size_t)h * SEQ + qrow) * HD + kk * 32 + kl * 8);

  f32x4 oacc[8] = {};
  float mrow[4] = {-1e30f, -1e30f, -1e30f, -1e30f};
  float lrow[4] = {0.f, 0.f, 0.f, 0.f};

  for (int kv0 = 0; kv0 < LTOT; kv0 += 64) {
#pragma unroll
    for (int it = 0; it < 4; ++it) {
      int slot = tid + it * 256;
      int j = slot & 63, dq = slot >> 6;
      int jg = kv0 + j;
      bf16x8 kvv = {0,0,0,0,0,0,0,0}, vvv = {0,0,0,0,0,0,0,0};
      if (jg < NCACHE) {
        const float* kp = Kc + ((size_t)jg * NH + h) * HD + dq * 8;
        const float* vp = Vc + ((size_t)jg * NH + h) * HD + dq * 8;
        f32x4 ka = *(const f32x4*)(kp), kb = *(const f32x4*)(kp + 4);
        f32x4 va = *(const f32x4*)(vp), vb = *(const f32x4*)(vp + 4);
#pragma unroll
        for (int i = 0; i < 4; ++i) {
          kvv[i] = (short)f2b(ka[i]); kvv[4 + i] = (short)f2b(kb[i]);
          vvv[i] = (short)f2b(va[i]); vvv[4 + i] = (short)f2b(vb[i]);
        }
      } else if (jg < LTOT) {
        kvv = *(const bf16x8*)(Kn + ((size_t)h * SEQ + (jg - NCACHE)) * HD + dq * 8);
        vvv = *(const bf16x8*)(Vn + ((size_t)h * SEQ + (jg - NCACHE)) * HD + dq * 8);
      }
      *(bf16x8*)&Kl[j][dq * 8] = kvv;
#pragma unroll
      for (int i = 0; i < 8; ++i) Vt[dq * 8 + i][j] = vvv[i];
    }
    __syncthreads();

    f32x4 sa[4] = {};
#pragma unroll
    for (int ni = 0; ni < 4; ++ni)
#pragma unroll
      for (int kk = 0; kk < 4; ++kk) {
        bf16x8 bK = *(const bf16x8*)&Kl[ni * 16 + l16][kk * 32 + kl * 8];
        sa[ni] = __builtin_amdgcn_mfma_f32_16x16x32_bf16(qf[kk], bK, sa[ni], 0, 0, 0);
      }

    float sv[4][4];
    float pm[4] = {-1e30f, -1e30f, -1e30f, -1e30f};
#pragma unroll
    for (int ni = 0; ni < 4; ++ni) {
      int jg = kv0 + ni * 16 + l16;
      bool valid = jg < LTOT;
#pragma unroll
      for (int r = 0; r < 4; ++r) {
        float xs = valid ? sa[ni][r] * SCALE : -1e30f;
        sv[ni][r] = xs;
        pm[r] = fmaxf(pm[r], xs);
      }
    }
#pragma unroll
    for (int off = 1; off < 16; off <<= 1)
#pragma unroll
      for (int r = 0; r < 4; ++r) pm[r] = fmaxf(pm[r], __shfl_xor(pm[r], off));

    float sc[4];
#pragma unroll
    for (int r = 0; r < 4; ++r) {
      float mn = fmaxf(mrow[r], pm[r]);
      sc[r] = __expf(mrow[r] - mn);
      mrow[r] = mn;
    }
    float ps[4] = {0.f, 0.f, 0.f, 0.f};
#pragma unroll
    for (int ni = 0; ni < 4; ++ni)
#pragma unroll
      for (int r = 0; r < 4; ++r) {
        float p = __expf(sv[ni][r] - mrow[r]);
        sv[ni][r] = p;
        ps[r] += p;
      }
#pragma unroll
    for (int off = 1; off < 16; off <<= 1)
#pragma unroll
      for (int r = 0; r < 4; ++r) ps[r] += __shfl_xor(ps[r], off);
#pragma unroll
    for (int r = 0; r < 4; ++r) lrow[r] = lrow[r] * sc[r] + ps[r];
#pragma unroll
    for (int di = 0; di < 8; ++di)
#pragma unroll
      for (int r = 0; r < 4; ++r) oacc[di][r] *= sc[r];
#pragma unroll
    for (int ni = 0; ni < 4; ++ni)
#pragma unroll
      for (int r = 0; r < 4; ++r)
        Pl[wv][kl * 4 + r][ni * 16 + l16] = (short)f2b(sv[ni][r]);
    __syncthreads();

#pragma unroll
    for (int di = 0; di < 8; ++di)
#pragma unroll
      for (int k2 = 0; k2 < 2; ++k2) {
        bf16x8 aP = *(const bf16x8*)&Pl[wv][l16][k2 * 32 + kl * 8];
        bf16x8 bV = *(const bf16x8*)&Vt[di * 16 + l16][k2 * 32 + kl * 8];
        oacc[di] = __builtin_amdgcn_mfma_f32_16x16x32_bf16(aP, bV, oacc[di], 0, 0, 0);
      }
    __syncthreads();
  }

  const int qb = qt * 64 + wv * 16 + kl * 4;
#pragma unroll
  for (int r = 0; r < 4; ++r) {
    int q = qb + r;
    if (q < SEQ) {
      float inv = 1.0f / lrow[r];
#pragma unroll
      for (int di = 0; di < 8; ++di)
        Qb[((size_t)h * SEQ + q) * HD + di * 16 + l16] = f2b(oacc[di][r] * inv);
    }
  }
}

extern "C" void kernel_launch(void* const* d_in, const int* in_sizes, int n_in,
                              void* d_out, int out_size, void* d_ws, size_t ws_size,
                              hipStream_t stream) {
  const float* x  = (const float*)d_in[0];
  const float* fr = (const float*)d_in[2];
  const float* Kc = (const float*)d_in[3];
  const float* Vc = (const float*)d_in[4];
  const float* Wq = (const float*)d_in[5];
  const float* bq = (const float*)d_in[6];
  const float* Wk = (const float*)d_in[7];
  const float* bk = (const float*)d_in[8];
  const float* Wv = (const float*)d_in[9];
  const float* bv = (const float*)d_in[10];
  const float* Wo = (const float*)d_in[11];
  const float* bo = (const float*)d_in[12];
  const float* gq = (const float*)d_in[13];
  const float* gk = (const float*)d_in[14];

  unsigned short* Qb = (unsigned short*)d_ws;
  unsigned short* Kn = Qb + (size_t)NH * SEQ * HD;
  unsigned short* Vn = Kn + (size_t)NH * SEQ * HD;
  const size_t baseB = (size_t)3 * NH * SEQ * HD * 2;   // 12.78 MB

  // tiered KV-split selection on ws_size (host-constant -> graph-deterministic)
  const size_t perSplitB = (size_t)NH * NQT * 64 * HD * 4       // Opart
                         + (size_t)NH * NQT * 2 * 64 * 4;       // ml
  int S = 0;
  if (ws_size >= baseB + 8 * perSplitB + (1 << 20)) S = 8;
  else if (ws_size >= baseB + 4 * perSplitB + (1 << 20)) S = 4;

  const dim3 gg(16, 9);
  gemm_k<<<gg, 256, 0, stream>>>(x, Wq, bq, Qb, 0, 2);
  gemm_k<<<gg, 256, 0, stream>>>(x, Wk, bk, Kn, 0, 2);
  gemm_k<<<gg, 256, 0, stream>>>(x, Wv, bv, Vn, 0, 2);
  rmsrope_k<<<dim3(SEQ, 2), 256, 0, stream>>>(Qb, Kn, gq, gk, fr);

  if (S > 0) {
    float* Opart = (float*)((char*)d_ws + baseB);
    float* ml    = Opart + (size_t)S * NH * NQT * 64 * HD;
    const int tiles = (LTOT + 63) / 64;                  // 147
    const int chunk = ((tiles + S - 1) / S) * 64;        // per-split kv rows
    attn_part_k<<<dim3(NQT, NH, S), 256, 0, stream>>>(Qb, Kn, Vn, Kc, Vc, Opart, ml, chunk);
    attn_merge_k<<<dim3(NQT, NH), 256, 0, stream>>>(Opart, ml, Qb, S);
  } else {
    attn_k<<<dim3(NQT, NH), 256, 0, stream>>>(Qb, Kn, Vn, Kc, Vc);
  }

  gemm_k<<<gg, 256, 0, stream>>>(Qb, Wo, bo, d_out, 1, 3);
}

// Round 13
// 718.193 us; speedup vs baseline: 1.6714x; 1.1918x over previous
//
#include <hip/hip_runtime.h>

using bf16x8 = __attribute__((ext_vector_type(8))) short;
using f32x4  = __attribute__((ext_vector_type(4))) float;

#define DEV static __device__ __forceinline__

constexpr int SEQ    = 1040;
constexpr int MDIM   = 2048;
constexpr int NH     = 16;
constexpr int HD     = 128;
constexpr int NCACHE = 8320;
constexpr int LTOT   = NCACHE + SEQ;   // 9360
constexpr int NQT    = 17;             // ceil(SEQ/64)

DEV float b2f(unsigned short u) {
  union { unsigned int i; float f; } z; z.i = ((unsigned int)u) << 16; return z.f;
}
DEV unsigned short f2b(float f) {
  union { float f; unsigned int i; } z; z.f = f;
  return (unsigned short)((z.i + 0x7fffu + ((z.i >> 16) & 1u)) >> 16);
}
// packed RNE fp32x2 -> bf16x2 (1 VALU inst vs ~6)
DEV unsigned int cvtpk(float lo, float hi) {
  unsigned int r;
  asm("v_cvt_pk_bf16_f32 %0, %1, %2" : "=v"(r) : "v"(lo), "v"(hi));
  return r;
}
union U4S8 { uint4 u; short s[8]; };

// ---------- fused QKV GEMM: N = 6144, grid (48, 9) ----------
__global__ __launch_bounds__(256) void gemm_qkv_k(
    const float* __restrict__ x,
    const float* __restrict__ Wq, const float* __restrict__ Wk, const float* __restrict__ Wv,
    const float* __restrict__ bq, const float* __restrict__ bk, const float* __restrict__ bv,
    unsigned short* __restrict__ Qb, unsigned short* __restrict__ Kn, unsigned short* __restrict__ Vn) {
  __shared__ short As[128][40];
  __shared__ short Bs[128][40];
  const int tid = threadIdx.x;
  const int l = tid & 63, wv = tid >> 6;
  const int l16 = l & 15, kl = l >> 4;
  const int m0 = blockIdx.y * 128;
  const int n0g = blockIdx.x * 128;
  const int which = n0g >> 11;               // 0:Q 1:K 2:V (block fully inside one W)
  const int n0 = n0g & 2047;
  const float* W = (which == 0) ? Wq : (which == 1) ? Wk : Wv;
  const float* bias = (which == 0) ? bq : (which == 1) ? bk : bv;
  unsigned short* outp = (which == 0) ? Qb : (which == 1) ? Kn : Vn;
  const int wm = (wv >> 1) * 64, wn = (wv & 1) * 64;
  const int nq = tid >> 4, kh = tid & 15;
  f32x4 acc[4][4] = {};
  for (int k0 = 0; k0 < MDIM; k0 += 32) {
#pragma unroll
    for (int it = 0; it < 2; ++it) {
      int slot = tid + it * 256;
      int m = slot >> 2, kq = slot & 3;
      int row = m0 + m, k = k0 + kq * 8;
      U4S8 v; v.u = make_uint4(0, 0, 0, 0);
      if (row < SEQ) {
        const float* Af = x + (size_t)row * MDIM + k;
        f32x4 f0 = *(const f32x4*)(Af);
        f32x4 f1 = *(const f32x4*)(Af + 4);
        v.u = make_uint4(cvtpk(f0[0], f0[1]), cvtpk(f0[2], f0[3]),
                         cvtpk(f1[0], f1[1]), cvtpk(f1[2], f1[3]));
      }
      *(uint4*)&As[m][kq * 8] = v.u;
    }
    {
      const float* Wp = W + (size_t)(k0 + kh * 2) * MDIM + n0 + nq * 8;
      f32x4 a0 = *(const f32x4*)(Wp);
      f32x4 a1 = *(const f32x4*)(Wp + 4);
      f32x4 b0 = *(const f32x4*)(Wp + MDIM);
      f32x4 b1 = *(const f32x4*)(Wp + MDIM + 4);
#pragma unroll
      for (int i = 0; i < 4; ++i) {
        *(unsigned int*)&Bs[nq * 8 + i][kh * 2] = cvtpk(a0[i], b0[i]);
        *(unsigned int*)&Bs[nq * 8 + 4 + i][kh * 2] = cvtpk(a1[i], b1[i]);
      }
    }
    __syncthreads();
    bf16x8 aF[4], bF[4];
#pragma unroll
    for (int mi = 0; mi < 4; ++mi)
      aF[mi] = *(const bf16x8*)&As[wm + mi * 16 + l16][kl * 8];
#pragma unroll
    for (int ni = 0; ni < 4; ++ni)
      bF[ni] = *(const bf16x8*)&Bs[wn + ni * 16 + l16][kl * 8];
#pragma unroll
    for (int mi = 0; mi < 4; ++mi)
#pragma unroll
      for (int ni = 0; ni < 4; ++ni)
        acc[mi][ni] = __builtin_amdgcn_mfma_f32_16x16x32_bf16(
            aF[mi], bF[ni], acc[mi][ni], 0, 0, 0);
    __syncthreads();
  }
#pragma unroll
  for (int ni = 0; ni < 4; ++ni) {
    const int col = n0 + wn + ni * 16 + l16;
    const float bb = bias[col];
#pragma unroll
    for (int mi = 0; mi < 4; ++mi) {
      const int rowb = m0 + wm + mi * 16 + kl * 4;
#pragma unroll
      for (int r = 0; r < 4; ++r) {
        const int row = rowb + r;
        if (row >= SEQ) continue;
        outp[((size_t)(col >> 7) * SEQ + row) * HD + (col & 127)] = f2b(acc[mi][ni][r] + bb);
      }
    }
  }
}

// ---------- GEMM for Wo (aLay1 in, fp32 out) — unchanged except cvt_pk B staging ----------
__global__ __launch_bounds__(256) void gemm_k(
    const void* __restrict__ Ap, const float* __restrict__ W,
    const float* __restrict__ bias, void* __restrict__ outp,
    int aLay, int oMode) {
  __shared__ short As[128][40];
  __shared__ short Bs[128][40];
  const int tid = threadIdx.x;
  const int l = tid & 63, wv = tid >> 6;
  const int l16 = l & 15, kl = l >> 4;
  const int m0 = blockIdx.y * 128, n0 = blockIdx.x * 128;
  const int wm = (wv >> 1) * 64, wn = (wv & 1) * 64;
  const int nq = tid >> 4, kh = tid & 15;
  f32x4 acc[4][4] = {};
  for (int k0 = 0; k0 < MDIM; k0 += 32) {
#pragma unroll
    for (int it = 0; it < 2; ++it) {
      int slot = tid + it * 256;
      int m = slot >> 2, kq = slot & 3;
      int row = m0 + m, k = k0 + kq * 8;
      bf16x8 v = {0, 0, 0, 0, 0, 0, 0, 0};
      if (row < SEQ) {
        if (aLay == 0) {
          const float* Af = (const float*)Ap + (size_t)row * MDIM + k;
          f32x4 f0 = *(const f32x4*)(Af);
          f32x4 f1 = *(const f32x4*)(Af + 4);
          U4S8 u; u.u = make_uint4(cvtpk(f0[0], f0[1]), cvtpk(f0[2], f0[3]),
                                   cvtpk(f1[0], f1[1]), cvtpk(f1[2], f1[3]));
#pragma unroll
          for (int i = 0; i < 8; ++i) v[i] = u.s[i];
        } else {
          const unsigned short* Ab = (const unsigned short*)Ap;
          v = *(const bf16x8*)(Ab + ((size_t)(k >> 7) * SEQ + row) * HD + (k & 127));
        }
      }
      *(bf16x8*)&As[m][kq * 8] = v;
    }
    {
      const float* Wp = W + (size_t)(k0 + kh * 2) * MDIM + n0 + nq * 8;
      f32x4 a0 = *(const f32x4*)(Wp);
      f32x4 a1 = *(const f32x4*)(Wp + 4);
      f32x4 b0 = *(const f32x4*)(Wp + MDIM);
      f32x4 b1 = *(const f32x4*)(Wp + MDIM + 4);
#pragma unroll
      for (int i = 0; i < 4; ++i) {
        *(unsigned int*)&Bs[nq * 8 + i][kh * 2] = cvtpk(a0[i], b0[i]);
        *(unsigned int*)&Bs[nq * 8 + 4 + i][kh * 2] = cvtpk(a1[i], b1[i]);
      }
    }
    __syncthreads();
    bf16x8 aF[4], bF[4];
#pragma unroll
    for (int mi = 0; mi < 4; ++mi)
      aF[mi] = *(const bf16x8*)&As[wm + mi * 16 + l16][kl * 8];
#pragma unroll
    for (int ni = 0; ni < 4; ++ni)
      bF[ni] = *(const bf16x8*)&Bs[wn + ni * 16 + l16][kl * 8];
#pragma unroll
    for (int mi = 0; mi < 4; ++mi)
#pragma unroll
      for (int ni = 0; ni < 4; ++ni)
        acc[mi][ni] = __builtin_amdgcn_mfma_f32_16x16x32_bf16(
            aF[mi], bF[ni], acc[mi][ni], 0, 0, 0);
    __syncthreads();
  }
#pragma unroll
  for (int ni = 0; ni < 4; ++ni) {
    const int col = n0 + wn + ni * 16 + l16;
    const float bb = bias[col];
#pragma unroll
    for (int mi = 0; mi < 4; ++mi) {
      const int rowb = m0 + wm + mi * 16 + kl * 4;
#pragma unroll
      for (int r = 0; r < 4; ++r) {
        const int row = rowb + r;
        if (row >= SEQ) continue;
        const float val = acc[mi][ni][r] + bb;
        if (oMode == 2) {
          ((unsigned short*)outp)[((size_t)(col >> 7) * SEQ + row) * HD + (col & 127)] = f2b(val);
        } else {
          ((float*)outp)[(size_t)row * MDIM + col] = val;
        }
      }
    }
  }
}

// ---------- RMSNorm + RoPE (unchanged, passing) ----------
__global__ __launch_bounds__(256) void rmsrope_k(
    unsigned short* __restrict__ Qb, unsigned short* __restrict__ Kn,
    const float* __restrict__ gq, const float* __restrict__ gk,
    const float* __restrict__ fr) {
  const int s = blockIdx.x, which = blockIdx.y;
  unsigned short* B = which ? Kn : Qb;
  const float* g = which ? gk : gq;
  __shared__ float cs[64], sn[64], red[4];
  const int t = threadIdx.x;
  if (t < 64) {
    float a = fr[s * 64 + t];
    cs[t] = cosf(a);
    sn[t] = sinf(a);
  }
  const int c0 = t * 8;
  const int hh = c0 >> 7, dd = c0 & 127, p0 = dd >> 1;
  const size_t addr = ((size_t)hh * SEQ + s) * HD + dd;
  bf16x8 v = *(const bf16x8*)(B + addr);
  float y[8];
#pragma unroll
  for (int i = 0; i < 8; ++i) y[i] = b2f((unsigned short)v[i]);
  float ssq = 0.f;
#pragma unroll
  for (int i = 0; i < 8; ++i) ssq += y[i] * y[i];
#pragma unroll
  for (int off = 32; off; off >>= 1) ssq += __shfl_xor(ssq, off);
  if ((t & 63) == 0) red[t >> 6] = ssq;
  __syncthreads();
  const float var = (red[0] + red[1] + red[2] + red[3]) * (1.0f / MDIM);
  const float rs = rsqrtf(var + 1e-6f);
  bf16x8 ov;
#pragma unroll
  for (int i = 0; i < 4; ++i) {
    float e = b2f(f2b(y[2 * i] * rs)) * g[c0 + 2 * i];
    float o = b2f(f2b(y[2 * i + 1] * rs)) * g[c0 + 2 * i + 1];
    float C = cs[p0 + i], S = sn[p0 + i];
    ov[2 * i]     = (short)f2b(e * C - o * S);
    ov[2 * i + 1] = (short)f2b(e * S + o * C);
  }
  *(bf16x8*)(B + addr) = ov;
}

// ---------- swizzle helpers: 16B-slot XOR within a row (T2) ----------
DEV int swzK(int row, int col) { return row * 128 + ((((col >> 3) ^ (row & 7)) << 3) | (col & 7)); }  // Kl[64][128]
DEV int swzV(int row, int col) { return row * 64  + ((((col >> 3) ^ (row & 7)) << 3) | (col & 7)); }  // Vt[128][64]
DEV int swzP(int row, int col) { return row * 64  + ((((col >> 3) ^ (row & 7)) << 3) | (col & 7)); }  // Pl[64][64]

// ---------- flash attention, KV-split partial kernel (swizzled, 40KB LDS) ----------
__global__ __launch_bounds__(256) void attn_part_k(
    const unsigned short* __restrict__ Qb, const unsigned short* __restrict__ Kn,
    const unsigned short* __restrict__ Vn, const float* __restrict__ Kc,
    const float* __restrict__ Vc, float* __restrict__ Opart,
    float* __restrict__ ml, int chunk) {
  __shared__ short Kl[64 * 128];   // 16 KB
  __shared__ short Vt[128 * 64];   // 16 KB
  __shared__ short Pl[64 * 64];    //  8 KB (4 waves x 16 rows)
  const int h = blockIdx.y, qt = blockIdx.x, z = blockIdx.z;
  const int tid = threadIdx.x, wv = tid >> 6, l = tid & 63;
  const int l16 = l & 15, kl = l >> 4;
  const float SCALE = 0.08838834764831845f;

  const int c0 = z * chunk;
  const int cend = min(c0 + chunk, LTOT);

  int qrow = qt * 64 + wv * 16 + l16;
  if (qrow > SEQ - 1) qrow = SEQ - 1;
  bf16x8 qf[4];
#pragma unroll
  for (int kk = 0; kk < 4; ++kk)
    qf[kk] = *(const bf16x8*)(Qb + ((size_t)h * SEQ + qrow) * HD + kk * 32 + kl * 8);

  f32x4 oacc[8] = {};
  float mrow[4] = {-1e30f, -1e30f, -1e30f, -1e30f};
  float lrow[4] = {0.f, 0.f, 0.f, 0.f};

  for (int kv0 = c0; kv0 < cend; kv0 += 64) {
#pragma unroll
    for (int it = 0; it < 4; ++it) {
      int slot = tid + it * 256;
      int j = slot & 63, dq = slot >> 6;
      int jg = kv0 + j;
      U4S8 ku, vu;
      ku.u = make_uint4(0, 0, 0, 0);
      vu.u = make_uint4(0, 0, 0, 0);
      if (jg < NCACHE) {
        const float* kp = Kc + ((size_t)jg * NH + h) * HD + dq * 8;
        const float* vp = Vc + ((size_t)jg * NH + h) * HD + dq * 8;
        f32x4 ka = *(const f32x4*)(kp), kb = *(const f32x4*)(kp + 4);
        f32x4 va = *(const f32x4*)(vp), vb = *(const f32x4*)(vp + 4);
        ku.u = make_uint4(cvtpk(ka[0], ka[1]), cvtpk(ka[2], ka[3]),
                          cvtpk(kb[0], kb[1]), cvtpk(kb[2], kb[3]));
        vu.u = make_uint4(cvtpk(va[0], va[1]), cvtpk(va[2], va[3]),
                          cvtpk(vb[0], vb[1]), cvtpk(vb[2], vb[3]));
      } else if (jg < LTOT) {
        ku.u = *(const uint4*)(Kn + ((size_t)h * SEQ + (jg - NCACHE)) * HD + dq * 8);
        vu.u = *(const uint4*)(Vn + ((size_t)h * SEQ + (jg - NCACHE)) * HD + dq * 8);
      }
      *(uint4*)&Kl[swzK(j, dq * 8)] = ku.u;     // swizzled 16B store
#pragma unroll
      for (int i = 0; i < 8; ++i) Vt[swzV(dq * 8 + i, j)] = vu.s[i];
    }
    __syncthreads();

    // S = Q K^T
    f32x4 sa[4] = {};
#pragma unroll
    for (int ni = 0; ni < 4; ++ni)
#pragma unroll
      for (int kk = 0; kk < 4; ++kk) {
        bf16x8 bK = *(const bf16x8*)&Kl[swzK(ni * 16 + l16, kk * 32 + kl * 8)];
        sa[ni] = __builtin_amdgcn_mfma_f32_16x16x32_bf16(qf[kk], bK, sa[ni], 0, 0, 0);
      }

    // online softmax
    float sv[4][4];
    float pm[4] = {-1e30f, -1e30f, -1e30f, -1e30f};
#pragma unroll
    for (int ni = 0; ni < 4; ++ni) {
      int jg = kv0 + ni * 16 + l16;
      bool valid = jg < LTOT;
#pragma unroll
      for (int r = 0; r < 4; ++r) {
        float xs = valid ? sa[ni][r] * SCALE : -1e30f;
        sv[ni][r] = xs;
        pm[r] = fmaxf(pm[r], xs);
      }
    }
#pragma unroll
    for (int off = 1; off < 16; off <<= 1)
#pragma unroll
      for (int r = 0; r < 4; ++r) pm[r] = fmaxf(pm[r], __shfl_xor(pm[r], off));

    float sc[4];
#pragma unroll
    for (int r = 0; r < 4; ++r) {
      float mn = fmaxf(mrow[r], pm[r]);
      sc[r] = __expf(mrow[r] - mn);
      mrow[r] = mn;
    }
    float ps[4] = {0.f, 0.f, 0.f, 0.f};
#pragma unroll
    for (int ni = 0; ni < 4; ++ni)
#pragma unroll
      for (int r = 0; r < 4; ++r) {
        float p = __expf(sv[ni][r] - mrow[r]);
        sv[ni][r] = p;
        ps[r] += p;
      }
#pragma unroll
    for (int off = 1; off < 16; off <<= 1)
#pragma unroll
      for (int r = 0; r < 4; ++r) ps[r] += __shfl_xor(ps[r], off);
#pragma unroll
    for (int r = 0; r < 4; ++r) lrow[r] = lrow[r] * sc[r] + ps[r];
#pragma unroll
    for (int di = 0; di < 8; ++di)
#pragma unroll
      for (int r = 0; r < 4; ++r) oacc[di][r] *= sc[r];
#pragma unroll
    for (int ni = 0; ni < 4; ++ni)
#pragma unroll
      for (int r = 0; r < 4; ++r)
        Pl[swzP(wv * 16 + kl * 4 + r, ni * 16 + l16)] = (short)f2b(sv[ni][r]);
    __syncthreads();

    // O += P V
#pragma unroll
    for (int di = 0; di < 8; ++di)
#pragma unroll
      for (int k2 = 0; k2 < 2; ++k2) {
        bf16x8 aP = *(const bf16x8*)&Pl[swzP(wv * 16 + l16, k2 * 32 + kl * 8)];
        bf16x8 bV = *(const bf16x8*)&Vt[swzV(di * 16 + l16, k2 * 32 + kl * 8)];
        oacc[di] = __builtin_amdgcn_mfma_f32_16x16x32_bf16(aP, bV, oacc[di], 0, 0, 0);
      }
    __syncthreads();
  }

  const size_t pbase = (((size_t)z * NH + h) * NQT + qt);
  const int rowb = wv * 16 + kl * 4;
#pragma unroll
  for (int r = 0; r < 4; ++r) {
    const int row = rowb + r;
    float* Op = Opart + (pbase * 64 + row) * HD;
#pragma unroll
    for (int di = 0; di < 8; ++di) Op[di * 16 + l16] = oacc[di][r];
    ml[(pbase * 2 + 0) * 64 + row] = mrow[r];
    ml[(pbase * 2 + 1) * 64 + row] = lrow[r];
  }
}

// ---------- merge partials -> bf16 O in Qb (unchanged, passing) ----------
__global__ __launch_bounds__(256) void attn_merge_k(
    const float* __restrict__ Opart, const float* __restrict__ ml,
    unsigned short* __restrict__ Qb, int S) {
  const int qt = blockIdx.x, h = blockIdx.y;
  const int t = threadIdx.x;
  const int row = t >> 2, d0 = (t & 3) * 32;
  const int q = qt * 64 + row;

  float M = -1e30f;
  for (int s = 0; s < S; ++s) {
    const size_t pbase = (((size_t)s * NH + h) * NQT + qt);
    M = fmaxf(M, ml[(pbase * 2 + 0) * 64 + row]);
  }
  float L = 0.f;
  float o[32];
#pragma unroll
  for (int i = 0; i < 32; ++i) o[i] = 0.f;
  for (int s = 0; s < S; ++s) {
    const size_t pbase = (((size_t)s * NH + h) * NQT + qt);
    const float ms = ml[(pbase * 2 + 0) * 64 + row];
    const float ls = ml[(pbase * 2 + 1) * 64 + row];
    const float w = __expf(ms - M);
    L += w * ls;
    const float* Op = Opart + (pbase * 64 + row) * HD + d0;
#pragma unroll
    for (int c = 0; c < 8; ++c) {
      f32x4 v = *(const f32x4*)(Op + c * 4);
#pragma unroll
      for (int i = 0; i < 4; ++i) o[c * 4 + i] += w * v[i];
    }
  }
  if (q < SEQ) {
    const float inv = 1.f / L;
    unsigned short* op = Qb + ((size_t)h * SEQ + q) * HD + d0;
#pragma unroll
    for (int i = 0; i < 32; ++i) op[i] = f2b(o[i] * inv);
  }
}

// ---------- fallback single-pass attention (known-passing, untouched) ----------
__global__ __launch_bounds__(256) void attn_k(
    unsigned short* __restrict__ Qb, const unsigned short* __restrict__ Kn,
    const unsigned short* __restrict__ Vn, const float* __restrict__ Kc,
    const float* __restrict__ Vc) {
  __shared__ short Kl[64][136];
  __shared__ short Vt[128][72];
  __shared__ short Pl[4][16][72];
  const int h = blockIdx.y, qt = blockIdx.x;
  const int tid = threadIdx.x, wv = tid >> 6, l = tid & 63;
  const int l16 = l & 15, kl = l >> 4;
  const float SCALE = 0.08838834764831845f;

  int qrow = qt * 64 + wv * 16 + l16;
  if (qrow > SEQ - 1) qrow = SEQ - 1;
  bf16x8 qf[4];
#pragma unroll
  for (int kk = 0; kk < 4; ++kk)
    qf[kk] = *(const bf16x8*)(Qb + ((size_t)h * SEQ + qrow) * HD + kk * 32 + kl * 8);

  f32x4 oacc[8] = {};
  float mrow[4] = {-1e30f, -1e30f, -1e30f, -1e30f};
  float lrow[4] = {0.f, 0.f, 0.f, 0.f};

  for (int kv0 = 0; kv0 < LTOT; kv0 += 64) {
#pragma unroll
    for (int it = 0; it < 4; ++it) {
      int slot = tid + it * 256;
      int j = slot & 63, dq = slot >> 6;
      int jg = kv0 + j;
      bf16x8 kvv = {0,0,0,0,0,0,0,0}, vvv = {0,0,0,0,0,0,0,0};
      if (jg < NCACHE) {
        const float* kp = Kc + ((size_t)jg * NH + h) * HD + dq * 8;
        const float* vp = Vc + ((size_t)jg * NH + h) * HD + dq * 8;
        f32x4 ka = *(const f32x4*)(kp), kb = *(const f32x4*)(kp + 4);
        f32x4 va = *(const f32x4*)(vp), vb = *(const f32x4*)(vp + 4);
#pragma unroll
        for (int i = 0; i < 4; ++i) {
          kvv[i] = (short)f2b(ka[i]); kvv[4 + i] = (short)f2b(kb[i]);
          vvv[i] = (short)f2b(va[i]); vvv[4 + i] = (short)f2b(vb[i]);
        }
      } else if (jg < LTOT) {
        kvv = *(const bf16x8*)(Kn + ((size_t)h * SEQ + (jg - NCACHE)) * HD + dq * 8);
        vvv = *(const bf16x8*)(Vn + ((size_t)h * SEQ + (jg - NCACHE)) * HD + dq * 8);
      }
      *(bf16x8*)&Kl[j][dq * 8] = kvv;
#pragma unroll
      for (int i = 0; i < 8; ++i) Vt[dq * 8 + i][j] = vvv[i];
    }
    __syncthreads();

    f32x4 sa[4] = {};
#pragma unroll
    for (int ni = 0; ni < 4; ++ni)
#pragma unroll
      for (int kk = 0; kk < 4; ++kk) {
        bf16x8 bK = *(const bf16x8*)&Kl[ni * 16 + l16][kk * 32 + kl * 8];
        sa[ni] = __builtin_amdgcn_mfma_f32_16x16x32_bf16(qf[kk], bK, sa[ni], 0, 0, 0);
      }

    float sv[4][4];
    float pm[4] = {-1e30f, -1e30f, -1e30f, -1e30f};
#pragma unroll
    for (int ni = 0; ni < 4; ++ni) {
      int jg = kv0 + ni * 16 + l16;
      bool valid = jg < LTOT;
#pragma unroll
      for (int r = 0; r < 4; ++r) {
        float xs = valid ? sa[ni][r] * SCALE : -1e30f;
        sv[ni][r] = xs;
        pm[r] = fmaxf(pm[r], xs);
      }
    }
#pragma unroll
    for (int off = 1; off < 16; off <<= 1)
#pragma unroll
      for (int r = 0; r < 4; ++r) pm[r] = fmaxf(pm[r], __shfl_xor(pm[r], off));

    float sc[4];
#pragma unroll
    for (int r = 0; r < 4; ++r) {
      float mn = fmaxf(mrow[r], pm[r]);
      sc[r] = __expf(mrow[r] - mn);
      mrow[r] = mn;
    }
    float ps[4] = {0.f, 0.f, 0.f, 0.f};
#pragma unroll
    for (int ni = 0; ni < 4; ++ni)
#pragma unroll
      for (int r = 0; r < 4; ++r) {
        float p = __expf(sv[ni][r] - mrow[r]);
        sv[ni][r] = p;
        ps[r] += p;
      }
#pragma unroll
    for (int off = 1; off < 16; off <<= 1)
#pragma unroll
      for (int r = 0; r < 4; ++r) ps[r] += __shfl_xor(ps[r], off);
#pragma unroll
    for (int r = 0; r < 4; ++r) lrow[r] = lrow[r] * sc[r] + ps[r];
#pragma unroll
    for (int di = 0; di < 8; ++di)
#pragma unroll
      for (int r = 0; r < 4; ++r) oacc[di][r] *= sc[r];
#pragma unroll
    for (int ni = 0; ni < 4; ++ni)
#pragma unroll
      for (int r = 0; r < 4; ++r)
        Pl[wv][kl * 4 + r][ni * 16 + l16] = (short)f2b(sv[ni][r]);
    __syncthreads();

#pragma unroll
    for (int di = 0; di < 8; ++di)
#pragma unroll
      for (int k2 = 0; k2 < 2; ++k2) {
        bf16x8 aP = *(const bf16x8*)&Pl[wv][l16][k2 * 32 + kl * 8];
        bf16x8 bV = *(const bf16x8*)&Vt[di * 16 + l16][k2 * 32 + kl * 8];
        oacc[di] = __builtin_amdgcn_mfma_f32_16x16x32_bf16(aP, bV, oacc[di], 0, 0, 0);
      }
    __syncthreads();
  }

  const int qb = qt * 64 + wv * 16 + kl * 4;
#pragma unroll
  for (int r = 0; r < 4; ++r) {
    int q = qb + r;
    if (q < SEQ) {
      float inv = 1.0f / lrow[r];
#pragma unroll
      for (int di = 0; di < 8; ++di)
        Qb[((size_t)h * SEQ + q) * HD + di * 16 + l16] = f2b(oacc[di][r] * inv);
    }
  }
}

extern "C" void kernel_launch(void* const* d_in, const int* in_sizes, int n_in,
                              void* d_out, int out_size, void* d_ws, size_t ws_size,
                              hipStream_t stream) {
  const float* x  = (const float*)d_in[0];
  const float* fr = (const float*)d_in[2];
  const float* Kc = (const float*)d_in[3];
  const float* Vc = (const float*)d_in[4];
  const float* Wq = (const float*)d_in[5];
  const float* bq = (const float*)d_in[6];
  const float* Wk = (const float*)d_in[7];
  const float* bk = (const float*)d_in[8];
  const float* Wv = (const float*)d_in[9];
  const float* bv = (const float*)d_in[10];
  const float* Wo = (const float*)d_in[11];
  const float* bo = (const float*)d_in[12];
  const float* gq = (const float*)d_in[13];
  const float* gk = (const float*)d_in[14];

  unsigned short* Qb = (unsigned short*)d_ws;
  unsigned short* Kn = Qb + (size_t)NH * SEQ * HD;
  unsigned short* Vn = Kn + (size_t)NH * SEQ * HD;
  const size_t baseB = (size_t)3 * NH * SEQ * HD * 2;

  const size_t perSplitB = (size_t)NH * NQT * 64 * HD * 4
                         + (size_t)NH * NQT * 2 * 64 * 4;
  int S = 0;
  if (ws_size >= baseB + 8 * perSplitB + (1 << 20)) S = 8;
  else if (ws_size >= baseB + 4 * perSplitB + (1 << 20)) S = 4;

  gemm_qkv_k<<<dim3(48, 9), 256, 0, stream>>>(x, Wq, Wk, Wv, bq, bk, bv, Qb, Kn, Vn);
  rmsrope_k<<<dim3(SEQ, 2), 256, 0, stream>>>(Qb, Kn, gq, gk, fr);

  if (S > 0) {
    float* Opart = (float*)((char*)d_ws + baseB);
    float* ml    = Opart + (size_t)S * NH * NQT * 64 * HD;
    const int tiles = (LTOT + 63) / 64;
    const int chunk = ((tiles + S - 1) / S) * 64;
    attn_part_k<<<dim3(NQT, NH, S), 256, 0, stream>>>(Qb, Kn, Vn, Kc, Vc, Opart, ml, chunk);
    attn_merge_k<<<dim3(NQT, NH), 256, 0, stream>>>(Opart, ml, Qb, S);
  } else {
    attn_k<<<dim3(NQT, NH), 256, 0, stream>>>(Qb, Kn, Vn, Kc, Vc);
  }

  gemm_k<<<dim3(16, 9), 256, 0, stream>>>(Qb, Wo, bo, d_out, 1, 3);
}

// Round 14
// 589.176 us; speedup vs baseline: 2.0374x; 1.2190x over previous
//
#include <hip/hip_runtime.h>

using bf16x8 = __attribute__((ext_vector_type(8))) short;
using f32x4  = __attribute__((ext_vector_type(4))) float;

#define DEV static __device__ __forceinline__

constexpr int SEQ    = 1040;
constexpr int MDIM   = 2048;
constexpr int NH     = 16;
constexpr int HD     = 128;
constexpr int NCACHE = 8320;
constexpr int LTOT   = NCACHE + SEQ;   // 9360
constexpr int NQT    = 17;             // ceil(SEQ/64)

DEV float b2f(unsigned short u) {
  union { unsigned int i; float f; } z; z.i = ((unsigned int)u) << 16; return z.f;
}
DEV unsigned short f2b(float f) {
  union { float f; unsigned int i; } z; z.f = f;
  return (unsigned short)((z.i + 0x7fffu + ((z.i >> 16) & 1u)) >> 16);
}
DEV unsigned int cvtpk(float lo, float hi) {
  unsigned int r;
  asm("v_cvt_pk_bf16_f32 %0, %1, %2" : "=v"(r) : "v"(lo), "v"(hi));
  return r;
}
union U4S8 { uint4 u; short s[8]; };

// ---------- fused QKV GEMM: N = 6144, grid (48, 9) (unchanged, passing) ----------
__global__ __launch_bounds__(256) void gemm_qkv_k(
    const float* __restrict__ x,
    const float* __restrict__ Wq, const float* __restrict__ Wk, const float* __restrict__ Wv,
    const float* __restrict__ bq, const float* __restrict__ bk, const float* __restrict__ bv,
    unsigned short* __restrict__ Qb, unsigned short* __restrict__ Kn, unsigned short* __restrict__ Vn) {
  __shared__ short As[128][40];
  __shared__ short Bs[128][40];
  const int tid = threadIdx.x;
  const int l = tid & 63, wv = tid >> 6;
  const int l16 = l & 15, kl = l >> 4;
  const int m0 = blockIdx.y * 128;
  const int n0g = blockIdx.x * 128;
  const int which = n0g >> 11;
  const int n0 = n0g & 2047;
  const float* W = (which == 0) ? Wq : (which == 1) ? Wk : Wv;
  const float* bias = (which == 0) ? bq : (which == 1) ? bk : bv;
  unsigned short* outp = (which == 0) ? Qb : (which == 1) ? Kn : Vn;
  const int wm = (wv >> 1) * 64, wn = (wv & 1) * 64;
  const int nq = tid >> 4, kh = tid & 15;
  f32x4 acc[4][4] = {};
  for (int k0 = 0; k0 < MDIM; k0 += 32) {
#pragma unroll
    for (int it = 0; it < 2; ++it) {
      int slot = tid + it * 256;
      int m = slot >> 2, kq = slot & 3;
      int row = m0 + m, k = k0 + kq * 8;
      U4S8 v; v.u = make_uint4(0, 0, 0, 0);
      if (row < SEQ) {
        const float* Af = x + (size_t)row * MDIM + k;
        f32x4 f0 = *(const f32x4*)(Af);
        f32x4 f1 = *(const f32x4*)(Af + 4);
        v.u = make_uint4(cvtpk(f0[0], f0[1]), cvtpk(f0[2], f0[3]),
                         cvtpk(f1[0], f1[1]), cvtpk(f1[2], f1[3]));
      }
      *(uint4*)&As[m][kq * 8] = v.u;
    }
    {
      const float* Wp = W + (size_t)(k0 + kh * 2) * MDIM + n0 + nq * 8;
      f32x4 a0 = *(const f32x4*)(Wp);
      f32x4 a1 = *(const f32x4*)(Wp + 4);
      f32x4 b0 = *(const f32x4*)(Wp + MDIM);
      f32x4 b1 = *(const f32x4*)(Wp + MDIM + 4);
#pragma unroll
      for (int i = 0; i < 4; ++i) {
        *(unsigned int*)&Bs[nq * 8 + i][kh * 2] = cvtpk(a0[i], b0[i]);
        *(unsigned int*)&Bs[nq * 8 + 4 + i][kh * 2] = cvtpk(a1[i], b1[i]);
      }
    }
    __syncthreads();
    bf16x8 aF[4], bF[4];
#pragma unroll
    for (int mi = 0; mi < 4; ++mi)
      aF[mi] = *(const bf16x8*)&As[wm + mi * 16 + l16][kl * 8];
#pragma unroll
    for (int ni = 0; ni < 4; ++ni)
      bF[ni] = *(const bf16x8*)&Bs[wn + ni * 16 + l16][kl * 8];
#pragma unroll
    for (int mi = 0; mi < 4; ++mi)
#pragma unroll
      for (int ni = 0; ni < 4; ++ni)
        acc[mi][ni] = __builtin_amdgcn_mfma_f32_16x16x32_bf16(
            aF[mi], bF[ni], acc[mi][ni], 0, 0, 0);
    __syncthreads();
  }
#pragma unroll
  for (int ni = 0; ni < 4; ++ni) {
    const int col = n0 + wn + ni * 16 + l16;
    const float bb = bias[col];
#pragma unroll
    for (int mi = 0; mi < 4; ++mi) {
      const int rowb = m0 + wm + mi * 16 + kl * 4;
#pragma unroll
      for (int r = 0; r < 4; ++r) {
        const int row = rowb + r;
        if (row >= SEQ) continue;
        outp[((size_t)(col >> 7) * SEQ + row) * HD + (col & 127)] = f2b(acc[mi][ni][r] + bb);
      }
    }
  }
}

// ---------- GEMM for Wo (unchanged, passing) ----------
__global__ __launch_bounds__(256) void gemm_k(
    const void* __restrict__ Ap, const float* __restrict__ W,
    const float* __restrict__ bias, void* __restrict__ outp,
    int aLay, int oMode) {
  __shared__ short As[128][40];
  __shared__ short Bs[128][40];
  const int tid = threadIdx.x;
  const int l = tid & 63, wv = tid >> 6;
  const int l16 = l & 15, kl = l >> 4;
  const int m0 = blockIdx.y * 128, n0 = blockIdx.x * 128;
  const int wm = (wv >> 1) * 64, wn = (wv & 1) * 64;
  const int nq = tid >> 4, kh = tid & 15;
  f32x4 acc[4][4] = {};
  for (int k0 = 0; k0 < MDIM; k0 += 32) {
#pragma unroll
    for (int it = 0; it < 2; ++it) {
      int slot = tid + it * 256;
      int m = slot >> 2, kq = slot & 3;
      int row = m0 + m, k = k0 + kq * 8;
      bf16x8 v = {0, 0, 0, 0, 0, 0, 0, 0};
      if (row < SEQ) {
        if (aLay == 0) {
          const float* Af = (const float*)Ap + (size_t)row * MDIM + k;
          f32x4 f0 = *(const f32x4*)(Af);
          f32x4 f1 = *(const f32x4*)(Af + 4);
          U4S8 u; u.u = make_uint4(cvtpk(f0[0], f0[1]), cvtpk(f0[2], f0[3]),
                                   cvtpk(f1[0], f1[1]), cvtpk(f1[2], f1[3]));
#pragma unroll
          for (int i = 0; i < 8; ++i) v[i] = u.s[i];
        } else {
          const unsigned short* Ab = (const unsigned short*)Ap;
          v = *(const bf16x8*)(Ab + ((size_t)(k >> 7) * SEQ + row) * HD + (k & 127));
        }
      }
      *(bf16x8*)&As[m][kq * 8] = v;
    }
    {
      const float* Wp = W + (size_t)(k0 + kh * 2) * MDIM + n0 + nq * 8;
      f32x4 a0 = *(const f32x4*)(Wp);
      f32x4 a1 = *(const f32x4*)(Wp + 4);
      f32x4 b0 = *(const f32x4*)(Wp + MDIM);
      f32x4 b1 = *(const f32x4*)(Wp + MDIM + 4);
#pragma unroll
      for (int i = 0; i < 4; ++i) {
        *(unsigned int*)&Bs[nq * 8 + i][kh * 2] = cvtpk(a0[i], b0[i]);
        *(unsigned int*)&Bs[nq * 8 + 4 + i][kh * 2] = cvtpk(a1[i], b1[i]);
      }
    }
    __syncthreads();
    bf16x8 aF[4], bF[4];
#pragma unroll
    for (int mi = 0; mi < 4; ++mi)
      aF[mi] = *(const bf16x8*)&As[wm + mi * 16 + l16][kl * 8];
#pragma unroll
    for (int ni = 0; ni < 4; ++ni)
      bF[ni] = *(const bf16x8*)&Bs[wn + ni * 16 + l16][kl * 8];
#pragma unroll
    for (int mi = 0; mi < 4; ++mi)
#pragma unroll
      for (int ni = 0; ni < 4; ++ni)
        acc[mi][ni] = __builtin_amdgcn_mfma_f32_16x16x32_bf16(
            aF[mi], bF[ni], acc[mi][ni], 0, 0, 0);
    __syncthreads();
  }
#pragma unroll
  for (int ni = 0; ni < 4; ++ni) {
    const int col = n0 + wn + ni * 16 + l16;
    const float bb = bias[col];
#pragma unroll
    for (int mi = 0; mi < 4; ++mi) {
      const int rowb = m0 + wm + mi * 16 + kl * 4;
#pragma unroll
      for (int r = 0; r < 4; ++r) {
        const int row = rowb + r;
        if (row >= SEQ) continue;
        const float val = acc[mi][ni][r] + bb;
        if (oMode == 2) {
          ((unsigned short*)outp)[((size_t)(col >> 7) * SEQ + row) * HD + (col & 127)] = f2b(val);
        } else {
          ((float*)outp)[(size_t)row * MDIM + col] = val;
        }
      }
    }
  }
}

// ---------- RMSNorm + RoPE (unchanged, passing) ----------
__global__ __launch_bounds__(256) void rmsrope_k(
    unsigned short* __restrict__ Qb, unsigned short* __restrict__ Kn,
    const float* __restrict__ gq, const float* __restrict__ gk,
    const float* __restrict__ fr) {
  const int s = blockIdx.x, which = blockIdx.y;
  unsigned short* B = which ? Kn : Qb;
  const float* g = which ? gk : gq;
  __shared__ float cs[64], sn[64], red[4];
  const int t = threadIdx.x;
  if (t < 64) {
    float a = fr[s * 64 + t];
    cs[t] = cosf(a);
    sn[t] = sinf(a);
  }
  const int c0 = t * 8;
  const int hh = c0 >> 7, dd = c0 & 127, p0 = dd >> 1;
  const size_t addr = ((size_t)hh * SEQ + s) * HD + dd;
  bf16x8 v = *(const bf16x8*)(B + addr);
  float y[8];
#pragma unroll
  for (int i = 0; i < 8; ++i) y[i] = b2f((unsigned short)v[i]);
  float ssq = 0.f;
#pragma unroll
  for (int i = 0; i < 8; ++i) ssq += y[i] * y[i];
#pragma unroll
  for (int off = 32; off; off >>= 1) ssq += __shfl_xor(ssq, off);
  if ((t & 63) == 0) red[t >> 6] = ssq;
  __syncthreads();
  const float var = (red[0] + red[1] + red[2] + red[3]) * (1.0f / MDIM);
  const float rs = rsqrtf(var + 1e-6f);
  bf16x8 ov;
#pragma unroll
  for (int i = 0; i < 4; ++i) {
    float e = b2f(f2b(y[2 * i] * rs)) * g[c0 + 2 * i];
    float o = b2f(f2b(y[2 * i + 1] * rs)) * g[c0 + 2 * i + 1];
    float C = cs[p0 + i], S = sn[p0 + i];
    ov[2 * i]     = (short)f2b(e * C - o * S);
    ov[2 * i + 1] = (short)f2b(e * S + o * C);
  }
  *(bf16x8*)(B + addr) = ov;
}

// ---------- flash attention, KV-split, XCD-grouped linear grid ----------
// r12 padded-LDS layout (the faster one) + cvtpk staging.
// Linear grid NQT*NH*S; decode puts all 17 qt-blocks of one (h,z) KV chunk
// consecutively on ONE XCD (b%8 == group%8) so they share its L2.
__global__ __launch_bounds__(256) void attn_part_k(
    const unsigned short* __restrict__ Qb, const unsigned short* __restrict__ Kn,
    const unsigned short* __restrict__ Vn, const float* __restrict__ Kc,
    const float* __restrict__ Vc, float* __restrict__ Opart,
    float* __restrict__ ml, int chunk, int S) {
  __shared__ short Kl[64][136];
  __shared__ short Vt[128][72];
  __shared__ short Pl[4][16][72];
  // XCD-group decode (requires 16*S % 8 == 0, S even)
  const int b = blockIdx.x;
  const int xcd = b & 7;
  const int r_ = b >> 3;
  const int qt = r_ % NQT;
  const int g = (r_ / NQT) * 8 + xcd;   // group id = z*NH + h
  const int h = g & (NH - 1);
  const int z = g >> 4;
  const int tid = threadIdx.x, wv = tid >> 6, l = tid & 63;
  const int l16 = l & 15, kl = l >> 4;
  const float SCALE = 0.08838834764831845f;

  const int c0 = z * chunk;
  const int cend = min(c0 + chunk, LTOT);

  int qrow = qt * 64 + wv * 16 + l16;
  if (qrow > SEQ - 1) qrow = SEQ - 1;
  bf16x8 qf[4];
#pragma unroll
  for (int kk = 0; kk < 4; ++kk)
    qf[kk] = *(const bf16x8*)(Qb + ((size_t)h * SEQ + qrow) * HD + kk * 32 + kl * 8);

  f32x4 oacc[8] = {};
  float mrow[4] = {-1e30f, -1e30f, -1e30f, -1e30f};
  float lrow[4] = {0.f, 0.f, 0.f, 0.f};

  for (int kv0 = c0; kv0 < cend; kv0 += 64) {
#pragma unroll
    for (int it = 0; it < 4; ++it) {
      int slot = tid + it * 256;
      int j = slot & 63, dq = slot >> 6;
      int jg = kv0 + j;
      U4S8 ku, vu;
      ku.u = make_uint4(0, 0, 0, 0);
      vu.u = make_uint4(0, 0, 0, 0);
      if (jg < NCACHE) {
        const float* kp = Kc + ((size_t)jg * NH + h) * HD + dq * 8;
        const float* vp = Vc + ((size_t)jg * NH + h) * HD + dq * 8;
        f32x4 ka = *(const f32x4*)(kp), kb = *(const f32x4*)(kp + 4);
        f32x4 va = *(const f32x4*)(vp), vb = *(const f32x4*)(vp + 4);
        ku.u = make_uint4(cvtpk(ka[0], ka[1]), cvtpk(ka[2], ka[3]),
                          cvtpk(kb[0], kb[1]), cvtpk(kb[2], kb[3]));
        vu.u = make_uint4(cvtpk(va[0], va[1]), cvtpk(va[2], va[3]),
                          cvtpk(vb[0], vb[1]), cvtpk(vb[2], vb[3]));
      } else if (jg < LTOT) {
        ku.u = *(const uint4*)(Kn + ((size_t)h * SEQ + (jg - NCACHE)) * HD + dq * 8);
        vu.u = *(const uint4*)(Vn + ((size_t)h * SEQ + (jg - NCACHE)) * HD + dq * 8);
      }
      *(uint4*)&Kl[j][dq * 8] = ku.u;
#pragma unroll
      for (int i = 0; i < 8; ++i) Vt[dq * 8 + i][j] = vu.s[i];
    }
    __syncthreads();

    f32x4 sa[4] = {};
#pragma unroll
    for (int ni = 0; ni < 4; ++ni)
#pragma unroll
      for (int kk = 0; kk < 4; ++kk) {
        bf16x8 bK = *(const bf16x8*)&Kl[ni * 16 + l16][kk * 32 + kl * 8];
        sa[ni] = __builtin_amdgcn_mfma_f32_16x16x32_bf16(qf[kk], bK, sa[ni], 0, 0, 0);
      }

    float sv[4][4];
    float pm[4] = {-1e30f, -1e30f, -1e30f, -1e30f};
#pragma unroll
    for (int ni = 0; ni < 4; ++ni) {
      int jg = kv0 + ni * 16 + l16;
      bool valid = jg < LTOT;
#pragma unroll
      for (int r = 0; r < 4; ++r) {
        float xs = valid ? sa[ni][r] * SCALE : -1e30f;
        sv[ni][r] = xs;
        pm[r] = fmaxf(pm[r], xs);
      }
    }
#pragma unroll
    for (int off = 1; off < 16; off <<= 1)
#pragma unroll
      for (int r = 0; r < 4; ++r) pm[r] = fmaxf(pm[r], __shfl_xor(pm[r], off));

    float sc[4];
#pragma unroll
    for (int r = 0; r < 4; ++r) {
      float mn = fmaxf(mrow[r], pm[r]);
      sc[r] = __expf(mrow[r] - mn);
      mrow[r] = mn;
    }
    float ps[4] = {0.f, 0.f, 0.f, 0.f};
#pragma unroll
    for (int ni = 0; ni < 4; ++ni)
#pragma unroll
      for (int r = 0; r < 4; ++r) {
        float p = __expf(sv[ni][r] - mrow[r]);
        sv[ni][r] = p;
        ps[r] += p;
      }
#pragma unroll
    for (int off = 1; off < 16; off <<= 1)
#pragma unroll
      for (int r = 0; r < 4; ++r) ps[r] += __shfl_xor(ps[r], off);
#pragma unroll
    for (int r = 0; r < 4; ++r) lrow[r] = lrow[r] * sc[r] + ps[r];
#pragma unroll
    for (int di = 0; di < 8; ++di)
#pragma unroll
      for (int r = 0; r < 4; ++r) oacc[di][r] *= sc[r];
#pragma unroll
    for (int ni = 0; ni < 4; ++ni)
#pragma unroll
      for (int r = 0; r < 4; ++r)
        Pl[wv][kl * 4 + r][ni * 16 + l16] = (short)f2b(sv[ni][r]);
    __syncthreads();

#pragma unroll
    for (int di = 0; di < 8; ++di)
#pragma unroll
      for (int k2 = 0; k2 < 2; ++k2) {
        bf16x8 aP = *(const bf16x8*)&Pl[wv][l16][k2 * 32 + kl * 8];
        bf16x8 bV = *(const bf16x8*)&Vt[di * 16 + l16][k2 * 32 + kl * 8];
        oacc[di] = __builtin_amdgcn_mfma_f32_16x16x32_bf16(aP, bV, oacc[di], 0, 0, 0);
      }
    __syncthreads();
  }

  const size_t pbase = (((size_t)z * NH + h) * NQT + qt);
  const int rowb = wv * 16 + kl * 4;
#pragma unroll
  for (int r = 0; r < 4; ++r) {
    const int row = rowb + r;
    float* Op = Opart + (pbase * 64 + row) * HD;
#pragma unroll
    for (int di = 0; di < 8; ++di) Op[di * 16 + l16] = oacc[di][r];
    ml[(pbase * 2 + 0) * 64 + row] = mrow[r];
    ml[(pbase * 2 + 1) * 64 + row] = lrow[r];
  }
}

// ---------- merge partials -> bf16 O in Qb (unchanged, passing) ----------
__global__ __launch_bounds__(256) void attn_merge_k(
    const float* __restrict__ Opart, const float* __restrict__ ml,
    unsigned short* __restrict__ Qb, int S) {
  const int qt = blockIdx.x, h = blockIdx.y;
  const int t = threadIdx.x;
  const int row = t >> 2, d0 = (t & 3) * 32;
  const int q = qt * 64 + row;

  float M = -1e30f;
  for (int s = 0; s < S; ++s) {
    const size_t pbase = (((size_t)s * NH + h) * NQT + qt);
    M = fmaxf(M, ml[(pbase * 2 + 0) * 64 + row]);
  }
  float L = 0.f;
  float o[32];
#pragma unroll
  for (int i = 0; i < 32; ++i) o[i] = 0.f;
  for (int s = 0; s < S; ++s) {
    const size_t pbase = (((size_t)s * NH + h) * NQT + qt);
    const float ms = ml[(pbase * 2 + 0) * 64 + row];
    const float ls = ml[(pbase * 2 + 1) * 64 + row];
    const float w = __expf(ms - M);
    L += w * ls;
    const float* Op = Opart + (pbase * 64 + row) * HD + d0;
#pragma unroll
    for (int c = 0; c < 8; ++c) {
      f32x4 v = *(const f32x4*)(Op + c * 4);
#pragma unroll
      for (int i = 0; i < 4; ++i) o[c * 4 + i] += w * v[i];
    }
  }
  if (q < SEQ) {
    const float inv = 1.f / L;
    unsigned short* op = Qb + ((size_t)h * SEQ + q) * HD + d0;
#pragma unroll
    for (int i = 0; i < 32; ++i) op[i] = f2b(o[i] * inv);
  }
}

// ---------- fallback single-pass attention (known-passing, untouched) ----------
__global__ __launch_bounds__(256) void attn_k(
    unsigned short* __restrict__ Qb, const unsigned short* __restrict__ Kn,
    const unsigned short* __restrict__ Vn, const float* __restrict__ Kc,
    const float* __restrict__ Vc) {
  __shared__ short Kl[64][136];
  __shared__ short Vt[128][72];
  __shared__ short Pl[4][16][72];
  const int h = blockIdx.y, qt = blockIdx.x;
  const int tid = threadIdx.x, wv = tid >> 6, l = tid & 63;
  const int l16 = l & 15, kl = l >> 4;
  const float SCALE = 0.08838834764831845f;

  int qrow = qt * 64 + wv * 16 + l16;
  if (qrow > SEQ - 1) qrow = SEQ - 1;
  bf16x8 qf[4];
#pragma unroll
  for (int kk = 0; kk < 4; ++kk)
    qf[kk] = *(const bf16x8*)(Qb + ((size_t)h * SEQ + qrow) * HD + kk * 32 + kl * 8);

  f32x4 oacc[8] = {};
  float mrow[4] = {-1e30f, -1e30f, -1e30f, -1e30f};
  float lrow[4] = {0.f, 0.f, 0.f, 0.f};

  for (int kv0 = 0; kv0 < LTOT; kv0 += 64) {
#pragma unroll
    for (int it = 0; it < 4; ++it) {
      int slot = tid + it * 256;
      int j = slot & 63, dq = slot >> 6;
      int jg = kv0 + j;
      bf16x8 kvv = {0,0,0,0,0,0,0,0}, vvv = {0,0,0,0,0,0,0,0};
      if (jg < NCACHE) {
        const float* kp = Kc + ((size_t)jg * NH + h) * HD + dq * 8;
        const float* vp = Vc + ((size_t)jg * NH + h) * HD + dq * 8;
        f32x4 ka = *(const f32x4*)(kp), kb = *(const f32x4*)(kp + 4);
        f32x4 va = *(const f32x4*)(vp), vb = *(const f32x4*)(vp + 4);
#pragma unroll
        for (int i = 0; i < 4; ++i) {
          kvv[i] = (short)f2b(ka[i]); kvv[4 + i] = (short)f2b(kb[i]);
          vvv[i] = (short)f2b(va[i]); vvv[4 + i] = (short)f2b(vb[i]);
        }
      } else if (jg < LTOT) {
        kvv = *(const bf16x8*)(Kn + ((size_t)h * SEQ + (jg - NCACHE)) * HD + dq * 8);
        vvv = *(const bf16x8*)(Vn + ((size_t)h * SEQ + (jg - NCACHE)) * HD + dq * 8);
      }
      *(bf16x8*)&Kl[j][dq * 8] = kvv;
#pragma unroll
      for (int i = 0; i < 8; ++i) Vt[dq * 8 + i][j] = vvv[i];
    }
    __syncthreads();

    f32x4 sa[4] = {};
#pragma unroll
    for (int ni = 0; ni < 4; ++ni)
#pragma unroll
      for (int kk = 0; kk < 4; ++kk) {
        bf16x8 bK = *(const bf16x8*)&Kl[ni * 16 + l16][kk * 32 + kl * 8];
        sa[ni] = __builtin_amdgcn_mfma_f32_16x16x32_bf16(qf[kk], bK, sa[ni], 0, 0, 0);
      }

    float sv[4][4];
    float pm[4] = {-1e30f, -1e30f, -1e30f, -1e30f};
#pragma unroll
    for (int ni = 0; ni < 4; ++ni) {
      int jg = kv0 + ni * 16 + l16;
      bool valid = jg < LTOT;
#pragma unroll
      for (int r = 0; r < 4; ++r) {
        float xs = valid ? sa[ni][r] * SCALE : -1e30f;
        sv[ni][r] = xs;
        pm[r] = fmaxf(pm[r], xs);
      }
    }
#pragma unroll
    for (int off = 1; off < 16; off <<= 1)
#pragma unroll
      for (int r = 0; r < 4; ++r) pm[r] = fmaxf(pm[r], __shfl_xor(pm[r], off));

    float sc[4];
#pragma unroll
    for (int r = 0; r < 4; ++r) {
      float mn = fmaxf(mrow[r], pm[r]);
      sc[r] = __expf(mrow[r] - mn);
      mrow[r] = mn;
    }
    float ps[4] = {0.f, 0.f, 0.f, 0.f};
#pragma unroll
    for (int ni = 0; ni < 4; ++ni)
#pragma unroll
      for (int r = 0; r < 4; ++r) {
        float p = __expf(sv[ni][r] - mrow[r]);
        sv[ni][r] = p;
        ps[r] += p;
      }
#pragma unroll
    for (int off = 1; off < 16; off <<= 1)
#pragma unroll
      for (int r = 0; r < 4; ++r) ps[r] += __shfl_xor(ps[r], off);
#pragma unroll
    for (int r = 0; r < 4; ++r) lrow[r] = lrow[r] * sc[r] + ps[r];
#pragma unroll
    for (int di = 0; di < 8; ++di)
#pragma unroll
      for (int r = 0; r < 4; ++r) oacc[di][r] *= sc[r];
#pragma unroll
    for (int ni = 0; ni < 4; ++ni)
#pragma unroll
      for (int r = 0; r < 4; ++r)
        Pl[wv][kl * 4 + r][ni * 16 + l16] = (short)f2b(sv[ni][r]);
    __syncthreads();

#pragma unroll
    for (int di = 0; di < 8; ++di)
#pragma unroll
      for (int k2 = 0; k2 < 2; ++k2) {
        bf16x8 aP = *(const bf16x8*)&Pl[wv][l16][k2 * 32 + kl * 8];
        bf16x8 bV = *(const bf16x8*)&Vt[di * 16 + l16][k2 * 32 + kl * 8];
        oacc[di] = __builtin_amdgcn_mfma_f32_16x16x32_bf16(aP, bV, oacc[di], 0, 0, 0);
      }
    __syncthreads();
  }

  const int qb = qt * 64 + wv * 16 + kl * 4;
#pragma unroll
  for (int r = 0; r < 4; ++r) {
    int q = qb + r;
    if (q < SEQ) {
      float inv = 1.0f / lrow[r];
#pragma unroll
      for (int di = 0; di < 8; ++di)
        Qb[((size_t)h * SEQ + q) * HD + di * 16 + l16] = f2b(oacc[di][r] * inv);
    }
  }
}

extern "C" void kernel_launch(void* const* d_in, const int* in_sizes, int n_in,
                              void* d_out, int out_size, void* d_ws, size_t ws_size,
                              hipStream_t stream) {
  const float* x  = (const float*)d_in[0];
  const float* fr = (const float*)d_in[2];
  const float* Kc = (const float*)d_in[3];
  const float* Vc = (const float*)d_in[4];
  const float* Wq = (const float*)d_in[5];
  const float* bq = (const float*)d_in[6];
  const float* Wk = (const float*)d_in[7];
  const float* bk = (const float*)d_in[8];
  const float* Wv = (const float*)d_in[9];
  const float* bv = (const float*)d_in[10];
  const float* Wo = (const float*)d_in[11];
  const float* bo = (const float*)d_in[12];
  const float* gq = (const float*)d_in[13];
  const float* gk = (const float*)d_in[14];

  unsigned short* Qb = (unsigned short*)d_ws;
  unsigned short* Kn = Qb + (size_t)NH * SEQ * HD;
  unsigned short* Vn = Kn + (size_t)NH * SEQ * HD;
  const size_t baseB = (size_t)3 * NH * SEQ * HD * 2;

  const size_t perSplitB = (size_t)NH * NQT * 64 * HD * 4
                         + (size_t)NH * NQT * 2 * 64 * 4;
  int S = 0;   // must stay even for the XCD-group decode
  if (ws_size >= baseB + 6 * perSplitB + (1 << 20)) S = 6;
  else if (ws_size >= baseB + 4 * perSplitB + (1 << 20)) S = 4;

  gemm_qkv_k<<<dim3(48, 9), 256, 0, stream>>>(x, Wq, Wk, Wv, bq, bk, bv, Qb, Kn, Vn);
  rmsrope_k<<<dim3(SEQ, 2), 256, 0, stream>>>(Qb, Kn, gq, gk, fr);

  if (S > 0) {
    float* Opart = (float*)((char*)d_ws + baseB);
    float* ml    = Opart + (size_t)S * NH * NQT * 64 * HD;
    const int tiles = (LTOT + 63) / 64;
    const int chunk = ((tiles + S - 1) / S) * 64;
    attn_part_k<<<dim3(NQT * NH * S), 256, 0, stream>>>(Qb, Kn, Vn, Kc, Vc, Opart, ml, chunk, S);
    attn_merge_k<<<dim3(NQT, NH), 256, 0, stream>>>(Opart, ml, Qb, S);
  } else {
    attn_k<<<dim3(NQT, NH), 256, 0, stream>>>(Qb, Kn, Vn, Kc, Vc);
  }

  gemm_k<<<dim3(16, 9), 256, 0, stream>>>(Qb, Wo, bo, d_out, 1, 3);
}

// Round 15
// 530.996 us; speedup vs baseline: 2.2606x; 1.1096x over previous
//
#include <hip/hip_runtime.h>

using bf16x8 = __attribute__((ext_vector_type(8))) short;
using f32x4  = __attribute__((ext_vector_type(4))) float;

#define DEV static __device__ __forceinline__

constexpr int SEQ    = 1040;
constexpr int MDIM   = 2048;
constexpr int NH     = 16;
constexpr int HD     = 128;
constexpr int NCACHE = 8320;
constexpr int LTOT   = NCACHE + SEQ;   // 9360
constexpr int NQT    = 17;             // ceil(SEQ/64)  (fallback kernel)
constexpr int NQT2   = 9;              // ceil(SEQ/128) (new kernel)

DEV float b2f(unsigned short u) {
  union { unsigned int i; float f; } z; z.i = ((unsigned int)u) << 16; return z.f;
}
DEV unsigned short f2b(float f) {
  union { float f; unsigned int i; } z; z.f = f;
  return (unsigned short)((z.i + 0x7fffu + ((z.i >> 16) & 1u)) >> 16);
}
DEV unsigned int cvtpk(float lo, float hi) {
  unsigned int r;
  asm("v_cvt_pk_bf16_f32 %0, %1, %2" : "=v"(r) : "v"(lo), "v"(hi));
  return r;
}
union U4S8 { uint4 u; short s[8]; };

// ---------- fused QKV GEMM: N = 6144, grid (48, 9) (unchanged, passing) ----------
__global__ __launch_bounds__(256) void gemm_qkv_k(
    const float* __restrict__ x,
    const float* __restrict__ Wq, const float* __restrict__ Wk, const float* __restrict__ Wv,
    const float* __restrict__ bq, const float* __restrict__ bk, const float* __restrict__ bv,
    unsigned short* __restrict__ Qb, unsigned short* __restrict__ Kn, unsigned short* __restrict__ Vn) {
  __shared__ short As[128][40];
  __shared__ short Bs[128][40];
  const int tid = threadIdx.x;
  const int l = tid & 63, wv = tid >> 6;
  const int l16 = l & 15, kl = l >> 4;
  const int m0 = blockIdx.y * 128;
  const int n0g = blockIdx.x * 128;
  const int which = n0g >> 11;
  const int n0 = n0g & 2047;
  const float* W = (which == 0) ? Wq : (which == 1) ? Wk : Wv;
  const float* bias = (which == 0) ? bq : (which == 1) ? bk : bv;
  unsigned short* outp = (which == 0) ? Qb : (which == 1) ? Kn : Vn;
  const int wm = (wv >> 1) * 64, wn = (wv & 1) * 64;
  const int nq = tid >> 4, kh = tid & 15;
  f32x4 acc[4][4] = {};
  for (int k0 = 0; k0 < MDIM; k0 += 32) {
#pragma unroll
    for (int it = 0; it < 2; ++it) {
      int slot = tid + it * 256;
      int m = slot >> 2, kq = slot & 3;
      int row = m0 + m, k = k0 + kq * 8;
      U4S8 v; v.u = make_uint4(0, 0, 0, 0);
      if (row < SEQ) {
        const float* Af = x + (size_t)row * MDIM + k;
        f32x4 f0 = *(const f32x4*)(Af);
        f32x4 f1 = *(const f32x4*)(Af + 4);
        v.u = make_uint4(cvtpk(f0[0], f0[1]), cvtpk(f0[2], f0[3]),
                         cvtpk(f1[0], f1[1]), cvtpk(f1[2], f1[3]));
      }
      *(uint4*)&As[m][kq * 8] = v.u;
    }
    {
      const float* Wp = W + (size_t)(k0 + kh * 2) * MDIM + n0 + nq * 8;
      f32x4 a0 = *(const f32x4*)(Wp);
      f32x4 a1 = *(const f32x4*)(Wp + 4);
      f32x4 b0 = *(const f32x4*)(Wp + MDIM);
      f32x4 b1 = *(const f32x4*)(Wp + MDIM + 4);
#pragma unroll
      for (int i = 0; i < 4; ++i) {
        *(unsigned int*)&Bs[nq * 8 + i][kh * 2] = cvtpk(a0[i], b0[i]);
        *(unsigned int*)&Bs[nq * 8 + 4 + i][kh * 2] = cvtpk(a1[i], b1[i]);
      }
    }
    __syncthreads();
    bf16x8 aF[4], bF[4];
#pragma unroll
    for (int mi = 0; mi < 4; ++mi)
      aF[mi] = *(const bf16x8*)&As[wm + mi * 16 + l16][kl * 8];
#pragma unroll
    for (int ni = 0; ni < 4; ++ni)
      bF[ni] = *(const bf16x8*)&Bs[wn + ni * 16 + l16][kl * 8];
#pragma unroll
    for (int mi = 0; mi < 4; ++mi)
#pragma unroll
      for (int ni = 0; ni < 4; ++ni)
        acc[mi][ni] = __builtin_amdgcn_mfma_f32_16x16x32_bf16(
            aF[mi], bF[ni], acc[mi][ni], 0, 0, 0);
    __syncthreads();
  }
#pragma unroll
  for (int ni = 0; ni < 4; ++ni) {
    const int col = n0 + wn + ni * 16 + l16;
    const float bb = bias[col];
#pragma unroll
    for (int mi = 0; mi < 4; ++mi) {
      const int rowb = m0 + wm + mi * 16 + kl * 4;
#pragma unroll
      for (int r = 0; r < 4; ++r) {
        const int row = rowb + r;
        if (row >= SEQ) continue;
        outp[((size_t)(col >> 7) * SEQ + row) * HD + (col & 127)] = f2b(acc[mi][ni][r] + bb);
      }
    }
  }
}

// ---------- GEMM for Wo (unchanged, passing) ----------
__global__ __launch_bounds__(256) void gemm_k(
    const void* __restrict__ Ap, const float* __restrict__ W,
    const float* __restrict__ bias, void* __restrict__ outp,
    int aLay, int oMode) {
  __shared__ short As[128][40];
  __shared__ short Bs[128][40];
  const int tid = threadIdx.x;
  const int l = tid & 63, wv = tid >> 6;
  const int l16 = l & 15, kl = l >> 4;
  const int m0 = blockIdx.y * 128, n0 = blockIdx.x * 128;
  const int wm = (wv >> 1) * 64, wn = (wv & 1) * 64;
  const int nq = tid >> 4, kh = tid & 15;
  f32x4 acc[4][4] = {};
  for (int k0 = 0; k0 < MDIM; k0 += 32) {
#pragma unroll
    for (int it = 0; it < 2; ++it) {
      int slot = tid + it * 256;
      int m = slot >> 2, kq = slot & 3;
      int row = m0 + m, k = k0 + kq * 8;
      bf16x8 v = {0, 0, 0, 0, 0, 0, 0, 0};
      if (row < SEQ) {
        if (aLay == 0) {
          const float* Af = (const float*)Ap + (size_t)row * MDIM + k;
          f32x4 f0 = *(const f32x4*)(Af);
          f32x4 f1 = *(const f32x4*)(Af + 4);
          U4S8 u; u.u = make_uint4(cvtpk(f0[0], f0[1]), cvtpk(f0[2], f0[3]),
                                   cvtpk(f1[0], f1[1]), cvtpk(f1[2], f1[3]));
#pragma unroll
          for (int i = 0; i < 8; ++i) v[i] = u.s[i];
        } else {
          const unsigned short* Ab = (const unsigned short*)Ap;
          v = *(const bf16x8*)(Ab + ((size_t)(k >> 7) * SEQ + row) * HD + (k & 127));
        }
      }
      *(bf16x8*)&As[m][kq * 8] = v;
    }
    {
      const float* Wp = W + (size_t)(k0 + kh * 2) * MDIM + n0 + nq * 8;
      f32x4 a0 = *(const f32x4*)(Wp);
      f32x4 a1 = *(const f32x4*)(Wp + 4);
      f32x4 b0 = *(const f32x4*)(Wp + MDIM);
      f32x4 b1 = *(const f32x4*)(Wp + MDIM + 4);
#pragma unroll
      for (int i = 0; i < 4; ++i) {
        *(unsigned int*)&Bs[nq * 8 + i][kh * 2] = cvtpk(a0[i], b0[i]);
        *(unsigned int*)&Bs[nq * 8 + 4 + i][kh * 2] = cvtpk(a1[i], b1[i]);
      }
    }
    __syncthreads();
    bf16x8 aF[4], bF[4];
#pragma unroll
    for (int mi = 0; mi < 4; ++mi)
      aF[mi] = *(const bf16x8*)&As[wm + mi * 16 + l16][kl * 8];
#pragma unroll
    for (int ni = 0; ni < 4; ++ni)
      bF[ni] = *(const bf16x8*)&Bs[wn + ni * 16 + l16][kl * 8];
#pragma unroll
    for (int mi = 0; mi < 4; ++mi)
#pragma unroll
      for (int ni = 0; ni < 4; ++ni)
        acc[mi][ni] = __builtin_amdgcn_mfma_f32_16x16x32_bf16(
            aF[mi], bF[ni], acc[mi][ni], 0, 0, 0);
    __syncthreads();
  }
#pragma unroll
  for (int ni = 0; ni < 4; ++ni) {
    const int col = n0 + wn + ni * 16 + l16;
    const float bb = bias[col];
#pragma unroll
    for (int mi = 0; mi < 4; ++mi) {
      const int rowb = m0 + wm + mi * 16 + kl * 4;
#pragma unroll
      for (int r = 0; r < 4; ++r) {
        const int row = rowb + r;
        if (row >= SEQ) continue;
        const float val = acc[mi][ni][r] + bb;
        if (oMode == 2) {
          ((unsigned short*)outp)[((size_t)(col >> 7) * SEQ + row) * HD + (col & 127)] = f2b(val);
        } else {
          ((float*)outp)[(size_t)row * MDIM + col] = val;
        }
      }
    }
  }
}

// ---------- RMSNorm + RoPE (unchanged, passing) ----------
__global__ __launch_bounds__(256) void rmsrope_k(
    unsigned short* __restrict__ Qb, unsigned short* __restrict__ Kn,
    const float* __restrict__ gq, const float* __restrict__ gk,
    const float* __restrict__ fr) {
  const int s = blockIdx.x, which = blockIdx.y;
  unsigned short* B = which ? Kn : Qb;
  const float* g = which ? gk : gq;
  __shared__ float cs[64], sn[64], red[4];
  const int t = threadIdx.x;
  if (t < 64) {
    float a = fr[s * 64 + t];
    cs[t] = cosf(a);
    sn[t] = sinf(a);
  }
  const int c0 = t * 8;
  const int hh = c0 >> 7, dd = c0 & 127, p0 = dd >> 1;
  const size_t addr = ((size_t)hh * SEQ + s) * HD + dd;
  bf16x8 v = *(const bf16x8*)(B + addr);
  float y[8];
#pragma unroll
  for (int i = 0; i < 8; ++i) y[i] = b2f((unsigned short)v[i]);
  float ssq = 0.f;
#pragma unroll
  for (int i = 0; i < 8; ++i) ssq += y[i] * y[i];
#pragma unroll
  for (int off = 32; off; off >>= 1) ssq += __shfl_xor(ssq, off);
  if ((t & 63) == 0) red[t >> 6] = ssq;
  __syncthreads();
  const float var = (red[0] + red[1] + red[2] + red[3]) * (1.0f / MDIM);
  const float rs = rsqrtf(var + 1e-6f);
  bf16x8 ov;
#pragma unroll
  for (int i = 0; i < 4; ++i) {
    float e = b2f(f2b(y[2 * i] * rs)) * g[c0 + 2 * i];
    float o = b2f(f2b(y[2 * i + 1] * rs)) * g[c0 + 2 * i + 1];
    float C = cs[p0 + i], S = sn[p0 + i];
    ov[2 * i]     = (short)f2b(e * C - o * S);
    ov[2 * i + 1] = (short)f2b(e * S + o * C);
  }
  *(bf16x8*)(B + addr) = ov;
}

// ---------- flash attention v2: QBLK=128, 8 waves, Pl aliased onto Kl ----------
// grid: linear NQT2*NH*S, XCD-grouped (all 9 qt-blocks of one (h,z) on one XCD).
// LDS: union{Kl[64][136], Pl[8][16][72]} (18,432B) + Vt[128][72] (18,432B) = 36KB.
__global__ __launch_bounds__(512) void attn_part2_k(
    const unsigned short* __restrict__ Qb, const unsigned short* __restrict__ Kn,
    const unsigned short* __restrict__ Vn, const float* __restrict__ Kc,
    const float* __restrict__ Vc, float* __restrict__ Opart,
    float* __restrict__ ml, int chunk, int S) {
  __shared__ short UN[9216];        // Kl: row j -> UN[j*136 + d]; Pl: UN[(w*16+r)*72 + c]
  __shared__ short Vt[128][72];
  const int b = blockIdx.x;
  const int xcd = b & 7;
  const int r_ = b >> 3;
  const int qt = r_ % NQT2;
  const int g = (r_ / NQT2) * 8 + xcd;   // group id = z*NH + h
  const int h = g & (NH - 1);
  const int z = g >> 4;
  const int tid = threadIdx.x, wv = tid >> 6, l = tid & 63;
  const int l16 = l & 15, kl = l >> 4;
  const float SCALE = 0.08838834764831845f;

  const int c0 = z * chunk;
  const int cend = min(c0 + chunk, LTOT);

  int qrow = qt * 128 + wv * 16 + l16;
  if (qrow > SEQ - 1) qrow = SEQ - 1;
  bf16x8 qf[4];
#pragma unroll
  for (int kk = 0; kk < 4; ++kk)
    qf[kk] = *(const bf16x8*)(Qb + ((size_t)h * SEQ + qrow) * HD + kk * 32 + kl * 8);

  f32x4 oacc[8] = {};
  float mrow[4] = {-1e30f, -1e30f, -1e30f, -1e30f};
  float lrow[4] = {0.f, 0.f, 0.f, 0.f};

  for (int kv0 = c0; kv0 < cend; kv0 += 64) {
    // ---- stage K into UN(Kl), V transposed into Vt (512 threads, 2 iters)
#pragma unroll
    for (int it = 0; it < 2; ++it) {
      int slot = tid + it * 512;
      int j = slot & 63, dq = slot >> 6;      // dq in [0,16)
      int jg = kv0 + j;
      U4S8 ku, vu;
      ku.u = make_uint4(0, 0, 0, 0);
      vu.u = make_uint4(0, 0, 0, 0);
      if (jg < NCACHE) {
        const float* kp = Kc + ((size_t)jg * NH + h) * HD + dq * 8;
        const float* vp = Vc + ((size_t)jg * NH + h) * HD + dq * 8;
        f32x4 ka = *(const f32x4*)(kp), kb = *(const f32x4*)(kp + 4);
        f32x4 va = *(const f32x4*)(vp), vb = *(const f32x4*)(vp + 4);
        ku.u = make_uint4(cvtpk(ka[0], ka[1]), cvtpk(ka[2], ka[3]),
                          cvtpk(kb[0], kb[1]), cvtpk(kb[2], kb[3]));
        vu.u = make_uint4(cvtpk(va[0], va[1]), cvtpk(va[2], va[3]),
                          cvtpk(vb[0], vb[1]), cvtpk(vb[2], vb[3]));
      } else if (jg < LTOT) {
        ku.u = *(const uint4*)(Kn + ((size_t)h * SEQ + (jg - NCACHE)) * HD + dq * 8);
        vu.u = *(const uint4*)(Vn + ((size_t)h * SEQ + (jg - NCACHE)) * HD + dq * 8);
      }
      *(uint4*)&UN[j * 136 + dq * 8] = ku.u;
#pragma unroll
      for (int i = 0; i < 8; ++i) Vt[dq * 8 + i][j] = vu.s[i];
    }
    __syncthreads();                                   // bar1: K/V staged

    // ---- S = Q K^T (reads UN as Kl)
    f32x4 sa[4] = {};
#pragma unroll
    for (int ni = 0; ni < 4; ++ni)
#pragma unroll
      for (int kk = 0; kk < 4; ++kk) {
        bf16x8 bK = *(const bf16x8*)&UN[(ni * 16 + l16) * 136 + kk * 32 + kl * 8];
        sa[ni] = __builtin_amdgcn_mfma_f32_16x16x32_bf16(qf[kk], bK, sa[ni], 0, 0, 0);
      }
    __syncthreads();                                   // bar2: all QK reads of Kl done (Pl aliases Kl)

    // ---- online softmax (registers only)
    float sv[4][4];
    float pm[4] = {-1e30f, -1e30f, -1e30f, -1e30f};
#pragma unroll
    for (int ni = 0; ni < 4; ++ni) {
      int jg = kv0 + ni * 16 + l16;
      bool valid = jg < LTOT;
#pragma unroll
      for (int r = 0; r < 4; ++r) {
        float xs = valid ? sa[ni][r] * SCALE : -1e30f;
        sv[ni][r] = xs;
        pm[r] = fmaxf(pm[r], xs);
      }
    }
#pragma unroll
    for (int off = 1; off < 16; off <<= 1)
#pragma unroll
      for (int r = 0; r < 4; ++r) pm[r] = fmaxf(pm[r], __shfl_xor(pm[r], off));

    float sc[4];
#pragma unroll
    for (int r = 0; r < 4; ++r) {
      float mn = fmaxf(mrow[r], pm[r]);
      sc[r] = __expf(mrow[r] - mn);
      mrow[r] = mn;
    }
    float ps[4] = {0.f, 0.f, 0.f, 0.f};
#pragma unroll
    for (int ni = 0; ni < 4; ++ni)
#pragma unroll
      for (int r = 0; r < 4; ++r) {
        float p = __expf(sv[ni][r] - mrow[r]);
        sv[ni][r] = p;
        ps[r] += p;
      }
#pragma unroll
    for (int off = 1; off < 16; off <<= 1)
#pragma unroll
      for (int r = 0; r < 4; ++r) ps[r] += __shfl_xor(ps[r], off);
#pragma unroll
    for (int r = 0; r < 4; ++r) lrow[r] = lrow[r] * sc[r] + ps[r];
#pragma unroll
    for (int di = 0; di < 8; ++di)
#pragma unroll
      for (int r = 0; r < 4; ++r) oacc[di][r] *= sc[r];
    // ---- write P into UN (Pl region, aliases Kl)
#pragma unroll
    for (int ni = 0; ni < 4; ++ni)
#pragma unroll
      for (int r = 0; r < 4; ++r)
        UN[(wv * 16 + kl * 4 + r) * 72 + ni * 16 + l16] = (short)f2b(sv[ni][r]);
    __syncthreads();                                   // bar3: P staged

    // ---- O += P V
#pragma unroll
    for (int di = 0; di < 8; ++di)
#pragma unroll
      for (int k2 = 0; k2 < 2; ++k2) {
        bf16x8 aP = *(const bf16x8*)&UN[(wv * 16 + l16) * 72 + k2 * 32 + kl * 8];
        bf16x8 bV = *(const bf16x8*)&Vt[di * 16 + l16][k2 * 32 + kl * 8];
        oacc[di] = __builtin_amdgcn_mfma_f32_16x16x32_bf16(aP, bV, oacc[di], 0, 0, 0);
      }
    __syncthreads();                                   // bar4: PV done before next stage
  }

  const size_t pbase = (((size_t)z * NH + h) * NQT2 + qt);
  const int row = wv * 16 + kl * 4;
#pragma unroll
  for (int r = 0; r < 4; ++r) {
    float* Op = Opart + (pbase * 128 + row + r) * HD;
#pragma unroll
    for (int di = 0; di < 8; ++di) Op[di * 16 + l16] = oacc[di][r];
    ml[(pbase * 2 + 0) * 128 + row + r] = mrow[r];
    ml[(pbase * 2 + 1) * 128 + row + r] = lrow[r];
  }
}

// ---------- merge partials (QBLK=128) -> bf16 O in Qb ----------
__global__ __launch_bounds__(512) void attn_merge2_k(
    const float* __restrict__ Opart, const float* __restrict__ ml,
    unsigned short* __restrict__ Qb, int S) {
  const int qt = blockIdx.x, h = blockIdx.y;
  const int t = threadIdx.x;
  const int row = t >> 2, d0 = (t & 3) * 32;
  const int q = qt * 128 + row;

  float M = -1e30f;
  for (int s = 0; s < S; ++s) {
    const size_t pbase = (((size_t)s * NH + h) * NQT2 + qt);
    M = fmaxf(M, ml[(pbase * 2 + 0) * 128 + row]);
  }
  float L = 0.f;
  float o[32];
#pragma unroll
  for (int i = 0; i < 32; ++i) o[i] = 0.f;
  for (int s = 0; s < S; ++s) {
    const size_t pbase = (((size_t)s * NH + h) * NQT2 + qt);
    const float ms = ml[(pbase * 2 + 0) * 128 + row];
    const float ls = ml[(pbase * 2 + 1) * 128 + row];
    const float w = __expf(ms - M);
    L += w * ls;
    const float* Op = Opart + (pbase * 128 + row) * HD + d0;
#pragma unroll
    for (int c = 0; c < 8; ++c) {
      f32x4 v = *(const f32x4*)(Op + c * 4);
#pragma unroll
      for (int i = 0; i < 4; ++i) o[c * 4 + i] += w * v[i];
    }
  }
  if (q < SEQ) {
    const float inv = 1.f / L;
    unsigned short* op = Qb + ((size_t)h * SEQ + q) * HD + d0;
#pragma unroll
    for (int i = 0; i < 32; ++i) op[i] = f2b(o[i] * inv);
  }
}

// ---------- fallback single-pass attention (known-passing, untouched) ----------
__global__ __launch_bounds__(256) void attn_k(
    unsigned short* __restrict__ Qb, const unsigned short* __restrict__ Kn,
    const unsigned short* __restrict__ Vn, const float* __restrict__ Kc,
    const float* __restrict__ Vc) {
  __shared__ short Kl[64][136];
  __shared__ short Vt[128][72];
  __shared__ short Pl[4][16][72];
  const int h = blockIdx.y, qt = blockIdx.x;
  const int tid = threadIdx.x, wv = tid >> 6, l = tid & 63;
  const int l16 = l & 15, kl = l >> 4;
  const float SCALE = 0.08838834764831845f;

  int qrow = qt * 64 + wv * 16 + l16;
  if (qrow > SEQ - 1) qrow = SEQ - 1;
  bf16x8 qf[4];
#pragma unroll
  for (int kk = 0; kk < 4; ++kk)
    qf[kk] = *(const bf16x8*)(Qb + ((size_t)h * SEQ + qrow) * HD + kk * 32 + kl * 8);

  f32x4 oacc[8] = {};
  float mrow[4] = {-1e30f, -1e30f, -1e30f, -1e30f};
  float lrow[4] = {0.f, 0.f, 0.f, 0.f};

  for (int kv0 = 0; kv0 < LTOT; kv0 += 64) {
#pragma unroll
    for (int it = 0; it < 4; ++it) {
      int slot = tid + it * 256;
      int j = slot & 63, dq = slot >> 6;
      int jg = kv0 + j;
      bf16x8 kvv = {0,0,0,0,0,0,0,0}, vvv = {0,0,0,0,0,0,0,0};
      if (jg < NCACHE) {
        const float* kp = Kc + ((size_t)jg * NH + h) * HD + dq * 8;
        const float* vp = Vc + ((size_t)jg * NH + h) * HD + dq * 8;
        f32x4 ka = *(const f32x4*)(kp), kb = *(const f32x4*)(kp + 4);
        f32x4 va = *(const f32x4*)(vp), vb = *(const f32x4*)(vp + 4);
#pragma unroll
        for (int i = 0; i < 4; ++i) {
          kvv[i] = (short)f2b(ka[i]); kvv[4 + i] = (short)f2b(kb[i]);
          vvv[i] = (short)f2b(va[i]); vvv[4 + i] = (short)f2b(vb[i]);
        }
      } else if (jg < LTOT) {
        kvv = *(const bf16x8*)(Kn + ((size_t)h * SEQ + (jg - NCACHE)) * HD + dq * 8);
        vvv = *(const bf16x8*)(Vn + ((size_t)h * SEQ + (jg - NCACHE)) * HD + dq * 8);
      }
      *(bf16x8*)&Kl[j][dq * 8] = kvv;
#pragma unroll
      for (int i = 0; i < 8; ++i) Vt[dq * 8 + i][j] = vvv[i];
    }
    __syncthreads();

    f32x4 sa[4] = {};
#pragma unroll
    for (int ni = 0; ni < 4; ++ni)
#pragma unroll
      for (int kk = 0; kk < 4; ++kk) {
        bf16x8 bK = *(const bf16x8*)&Kl[ni * 16 + l16][kk * 32 + kl * 8];
        sa[ni] = __builtin_amdgcn_mfma_f32_16x16x32_bf16(qf[kk], bK, sa[ni], 0, 0, 0);
      }

    float sv[4][4];
    float pm[4] = {-1e30f, -1e30f, -1e30f, -1e30f};
#pragma unroll
    for (int ni = 0; ni < 4; ++ni) {
      int jg = kv0 + ni * 16 + l16;
      bool valid = jg < LTOT;
#pragma unroll
      for (int r = 0; r < 4; ++r) {
        float xs = valid ? sa[ni][r] * SCALE : -1e30f;
        sv[ni][r] = xs;
        pm[r] = fmaxf(pm[r], xs);
      }
    }
#pragma unroll
    for (int off = 1; off < 16; off <<= 1)
#pragma unroll
      for (int r = 0; r < 4; ++r) pm[r] = fmaxf(pm[r], __shfl_xor(pm[r], off));

    float sc[4];
#pragma unroll
    for (int r = 0; r < 4; ++r) {
      float mn = fmaxf(mrow[r], pm[r]);
      sc[r] = __expf(mrow[r] - mn);
      mrow[r] = mn;
    }
    float ps[4] = {0.f, 0.f, 0.f, 0.f};
#pragma unroll
    for (int ni = 0; ni < 4; ++ni)
#pragma unroll
      for (int r = 0; r < 4; ++r) {
        float p = __expf(sv[ni][r] - mrow[r]);
        sv[ni][r] = p;
        ps[r] += p;
      }
#pragma unroll
    for (int off = 1; off < 16; off <<= 1)
#pragma unroll
      for (int r = 0; r < 4; ++r) ps[r] += __shfl_xor(ps[r], off);
#pragma unroll
    for (int r = 0; r < 4; ++r) lrow[r] = lrow[r] * sc[r] + ps[r];
#pragma unroll
    for (int di = 0; di < 8; ++di)
#pragma unroll
      for (int r = 0; r < 4; ++r) oacc[di][r] *= sc[r];
#pragma unroll
    for (int ni = 0; ni < 4; ++ni)
#pragma unroll
      for (int r = 0; r < 4; ++r)
        Pl[wv][kl * 4 + r][ni * 16 + l16] = (short)f2b(sv[ni][r]);
    __syncthreads();

#pragma unroll
    for (int di = 0; di < 8; ++di)
#pragma unroll
      for (int k2 = 0; k2 < 2; ++k2) {
        bf16x8 aP = *(const bf16x8*)&Pl[wv][l16][k2 * 32 + kl * 8];
        bf16x8 bV = *(const bf16x8*)&Vt[di * 16 + l16][k2 * 32 + kl * 8];
        oacc[di] = __builtin_amdgcn_mfma_f32_16x16x32_bf16(aP, bV, oacc[di], 0, 0, 0);
      }
    __syncthreads();
  }

  const int qb = qt * 64 + wv * 16 + kl * 4;
#pragma unroll
  for (int r = 0; r < 4; ++r) {
    int q = qb + r;
    if (q < SEQ) {
      float inv = 1.0f / lrow[r];
#pragma unroll
      for (int di = 0; di < 8; ++di)
        Qb[((size_t)h * SEQ + q) * HD + di * 16 + l16] = f2b(oacc[di][r] * inv);
    }
  }
}

extern "C" void kernel_launch(void* const* d_in, const int* in_sizes, int n_in,
                              void* d_out, int out_size, void* d_ws, size_t ws_size,
                              hipStream_t stream) {
  const float* x  = (const float*)d_in[0];
  const float* fr = (const float*)d_in[2];
  const float* Kc = (const float*)d_in[3];
  const float* Vc = (const float*)d_in[4];
  const float* Wq = (const float*)d_in[5];
  const float* bq = (const float*)d_in[6];
  const float* Wk = (const float*)d_in[7];
  const float* bk = (const float*)d_in[8];
  const float* Wv = (const float*)d_in[9];
  const float* bv = (const float*)d_in[10];
  const float* Wo = (const float*)d_in[11];
  const float* bo = (const float*)d_in[12];
  const float* gq = (const float*)d_in[13];
  const float* gk = (const float*)d_in[14];

  unsigned short* Qb = (unsigned short*)d_ws;
  unsigned short* Kn = Qb + (size_t)NH * SEQ * HD;
  unsigned short* Vn = Kn + (size_t)NH * SEQ * HD;
  const size_t baseB = (size_t)3 * NH * SEQ * HD * 2;

  // QBLK=128 partials: per-split = Opart(16*9*128*128*4) + ml(16*9*2*128*4)
  const size_t perSplitB = (size_t)NH * NQT2 * 128 * HD * 4
                         + (size_t)NH * NQT2 * 2 * 128 * 4;
  int S = 0;
  if (ws_size >= baseB + 8 * perSplitB + (1 << 20)) S = 8;
  else if (ws_size >= baseB + 7 * perSplitB + (1 << 20)) S = 7;  // guaranteed: ws >= 86 MB (r12 S=8 tier fired)
  else if (ws_size >= baseB + 4 * perSplitB + (1 << 20)) S = 4;

  gemm_qkv_k<<<dim3(48, 9), 256, 0, stream>>>(x, Wq, Wk, Wv, bq, bk, bv, Qb, Kn, Vn);
  rmsrope_k<<<dim3(SEQ, 2), 256, 0, stream>>>(Qb, Kn, gq, gk, fr);

  if (S > 0) {
    float* Opart = (float*)((char*)d_ws + baseB);
    float* ml    = Opart + (size_t)S * NH * NQT2 * 128 * HD;
    const int tiles = (LTOT + 63) / 64;                // 147
    const int chunk = ((tiles + S - 1) / S) * 64;
    attn_part2_k<<<dim3(NQT2 * NH * S), 512, 0, stream>>>(Qb, Kn, Vn, Kc, Vc, Opart, ml, chunk, S);
    attn_merge2_k<<<dim3(NQT2, NH), 512, 0, stream>>>(Opart, ml, Qb, S);
  } else {
    attn_k<<<dim3(NQT, NH), 256, 0, stream>>>(Qb, Kn, Vn, Kc, Vc);
  }

  gemm_k<<<dim3(16, 9), 256, 0, stream>>>(Qb, Wo, bo, d_out, 1, 3);
}